// Round 9
// baseline (1463.587 us; speedup 1.0000x reference)
//
#include <hip/hip_runtime.h>
#include <hip/hip_bf16.h>
#include <math.h>

// Problem constants (fixed by the reference)
#define TT   799
#define BB   8
#define DD   512
#define HH   8
#define HDD  64
#define MMEM 6
#define RRCB 24
#define KLL  798
#define TQ   798            // query rows actually needed (row 798 unused)
#define NROWS (TQ * BB)     // 6384
#define NHEADS 64           // B*H
#define NEG_INF (-INFINITY)

#define TB   16             // t-rows per attention block
#define CH   64             // keys per MFMA chunk
#define NCH  13             // 13*64 = 832 >= 798

static_assert(NROWS == 6384, "");

typedef __attribute__((ext_vector_type(8))) short short8;
typedef __attribute__((ext_vector_type(4))) float f32x4;

__device__ __forceinline__ unsigned short f2bf(float x) {
    union { float f; unsigned u; } c; c.f = x;
    unsigned r = c.u + 0x7FFFu + ((c.u >> 16) & 1u);   // RNE
    return (unsigned short)(r >> 16);
}
__device__ __forceinline__ float bf2f(unsigned short b) {
    union { unsigned u; float f; } c; c.u = ((unsigned)b) << 16; return c.f;
}

// Classify attention_mask storage from byte patterns (sampled prefix).
// mode 0 = int32 (0/1), mode 1 = float32 (0.0/1.0), mode 2 = uint8 bool.
__global__ void detect_mask_kernel(const unsigned int* __restrict__ a,
                                   int* __restrict__ mode)
{
    __shared__ int c0s, cHs;
    if (threadIdx.x == 0) { c0s = 0; cHs = 0; }
    __syncthreads();
    int c0 = 0, cH = 0;
    const int ND = 4096;
    for (int i = threadIdx.x; i < ND; i += blockDim.x) {
        unsigned int w = a[i];
        if (w & 0x000000FFu) c0++;
        if (w & 0xFFFFFF00u) cH++;
    }
    atomicAdd(&c0s, c0); atomicAdd(&cHs, cH);
    __syncthreads();
    if (threadIdx.x == 0)
        *mode = (cHs == 0) ? 0 : ((c0s == 0) ? 1 : 2);
}

// Pack (mask, rpe) -> byte: rid 0..128 if unmasked, 255 if masked.
// Layout: pk[t][0..799], row stride 800 bytes (dword-aligned).
__global__ __launch_bounds__(256)
void pack_kernel(const void* __restrict__ amask,
                 const int* __restrict__ rpe,
                 const int* __restrict__ mode_p,
                 unsigned int* __restrict__ pk)
{
    const int mode = *mode_p;
    const int NW = TT * 200;           // dwords
    int i = blockIdx.x * 256 + threadIdx.x;
    if (i >= NW) return;
    int t = i / 200;
    int kbase = (i - t * 200) * 4;
    unsigned out = 0;
    #pragma unroll
    for (int u = 0; u < 4; ++u) {
        int k = kbase + u;
        unsigned byte = 255u;
        if (k < KLL) {
            size_t idx = (size_t)t * KLL + k;
            bool masked;
            if (mode == 0)      masked = (((const int*)amask)[idx] != 0);
            else if (mode == 1) masked = (((const float*)amask)[idx] != 0.f);
            else                masked = (((const unsigned char*)amask)[idx] != 0);
            byte = masked ? 255u : (unsigned)rpe[idx];
        }
        out |= byte << (8 * u);
    }
    pk[i] = out;
}

// MODE 0: q = x @ wq^T + bq  (scaled by 0.125, stored f32 (BH,798,64))
// MODE 1: kv = mem_rc @ wkv^T + bkv; k stored as bf16 hi/lo, v stored f32
template<int MODE>
__global__ __launch_bounds__(256)
void proj_kernel(const float* __restrict__ x,
                 const float* __restrict__ mems,
                 const float* __restrict__ w,
                 const float* __restrict__ bias,
                 float* __restrict__ q_s,
                 unsigned short* __restrict__ k_hi,
                 unsigned short* __restrict__ k_lo,
                 float* __restrict__ v_s)
{
    __shared__ float As[16][65];
    __shared__ float Ws[16][65];
    const int tid = threadIdx.x;
    const int m0 = blockIdx.x * 64;
    const int n0 = blockIdx.y * 64;
    const int tx = tid & 15;
    const int ty = tid >> 4;
    float acc[4][4] = {};

    for (int k0 = 0; k0 < DD; k0 += 16) {
        #pragma unroll
        for (int i = 0; i < 4; ++i) {
            int idx = tid + i * 256;
            int kk = idx & 15;
            int mm = idx >> 4;
            int m = m0 + mm;
            float va = 0.f;
            if (m < NROWS) {
                int row = m >> 3, b = m & 7;
                const float* src;
                if (MODE == 0) src = x + ((size_t)row * BB + b) * DD;
                else src = (row < MMEM) ? (mems + ((size_t)row * BB + b) * DD)
                                        : (x + ((size_t)(row - MMEM) * BB + b) * DD);
                va = src[k0 + kk];
            }
            As[kk][mm] = va;
            int n = n0 + mm;
            Ws[kk][mm] = w[(size_t)n * DD + k0 + kk];
        }
        __syncthreads();
        #pragma unroll
        for (int kk = 0; kk < 16; ++kk) {
            float a[4], wv[4];
            #pragma unroll
            for (int i = 0; i < 4; ++i) a[i] = As[kk][ty * 4 + i];
            #pragma unroll
            for (int j = 0; j < 4; ++j) wv[j] = Ws[kk][tx * 4 + j];
            #pragma unroll
            for (int i = 0; i < 4; ++i)
                #pragma unroll
                for (int j = 0; j < 4; ++j)
                    acc[i][j] = fmaf(a[i], wv[j], acc[i][j]);
        }
        __syncthreads();
    }

    #pragma unroll
    for (int i = 0; i < 4; ++i) {
        int m = m0 + ty * 4 + i;
        if (m >= NROWS) continue;
        int row = m >> 3, b = m & 7;
        #pragma unroll
        for (int j = 0; j < 4; ++j) {
            int n = n0 + tx * 4 + j;
            float v = acc[i][j] + bias[n];
            if (MODE == 0) {
                int h = n >> 6, hd = n & 63;
                q_s[((size_t)(b * HH + h) * TQ + row) * HDD + hd] = v * 0.125f;
            } else {
                if (n < DD) {
                    int h = n >> 6, hd = n & 63;
                    size_t o = ((size_t)(b * HH + h) * KLL + row) * HDD + hd;
                    unsigned short hi = f2bf(v);
                    k_hi[o] = hi;
                    k_lo[o] = f2bf(v - bf2f(hi));
                } else {
                    int n2 = n - DD;
                    int h = n2 >> 6, hd = n2 & 63;
                    v_s[((size_t)(b * HH + h) * KLL + row) * HDD + hd] = v;
                }
            }
        }
    }
}

// Attention v5b: MFMA QK^T with direct-global B-frags (zero-barrier pass A),
// scores cached in registers, packed rid/mask byte table in LDS,
// light pass B (exp + threshold + PV). Pass B guarded by s > -1e29 so
// padding rows / masked keys / key>=klen are inert (p==0 -> no atomic,
// no V read) — R8's OOB-LDS NaN bug fix.
__global__ __launch_bounds__(256, 4)
void attn_kernel(const float* __restrict__ q_s,
                 const unsigned short* __restrict__ kh_g,
                 const unsigned short* __restrict__ kl_g,
                 const float* __restrict__ v_s,
                 const int* __restrict__ lengths,
                 const unsigned char* __restrict__ pk,
                 const float* __restrict__ rpe_k,
                 const float* __restrict__ rpe_v,
                 float* __restrict__ attn_buf)
{
    const int t0 = blockIdx.x * TB;
    const int rows = min(TB, TQ - t0);
    const int n = blockIdx.y;
    const int b = n >> 3;
    const int h = n & 7;
    const int tid = threadIdx.x;
    const int wv = tid >> 6;            // wave -> 16-key slice within chunk
    const int quad = (tid >> 4) & 3;    // MFMA quad
    const int colk = tid & 15;
    const int r16 = tid >> 4;           // row lane mapping for qrk/PV
    const int g = tid & 15;             // hd quad

    __shared__ unsigned short qh_l[TB][72];                 // 2304 B
    __shared__ unsigned short ql_l[TB][72];                 // 2304 B
    __shared__ __align__(16) float qf_l[TB][68];            // 4352 B (q f32 -> p_ch)
    __shared__ float qrk_l[TB][132];                        // 8448 B (qrk -> pr)
    __shared__ unsigned char pk_l[TB][800];                 // 12800 B
    __shared__ float4 stats_l[4][TB];                       // 1024 B

    const int klen = lengths[b] + MMEM + RRCB;

    // phase 0: q tile (f32 + bf16 hi/lo) and pk tile -> LDS
    for (int i = tid; i < TB * 16; i += 256) {
        int rr = i >> 4, j4 = i & 15;
        float4 v = {0.f, 0.f, 0.f, 0.f};
        if (rr < rows) v = *(const float4*)(q_s + ((size_t)n * TQ + t0 + rr) * HDD + j4 * 4);
        *(float4*)&qf_l[rr][j4 * 4] = v;
        unsigned short h0 = f2bf(v.x), h1 = f2bf(v.y), h2 = f2bf(v.z), h3 = f2bf(v.w);
        qh_l[rr][j4 * 4 + 0] = h0; qh_l[rr][j4 * 4 + 1] = h1;
        qh_l[rr][j4 * 4 + 2] = h2; qh_l[rr][j4 * 4 + 3] = h3;
        ql_l[rr][j4 * 4 + 0] = f2bf(v.x - bf2f(h0));
        ql_l[rr][j4 * 4 + 1] = f2bf(v.y - bf2f(h1));
        ql_l[rr][j4 * 4 + 2] = f2bf(v.z - bf2f(h2));
        ql_l[rr][j4 * 4 + 3] = f2bf(v.w - bf2f(h3));
    }
    for (int i = tid; i < TB * 200; i += 256) {
        int rr = i / 200, dw = i - rr * 200;
        unsigned w = 0xFFFFFFFFu;
        if (rr < rows) w = ((const unsigned*)pk)[(t0 + rr) * 200 + dw];
        ((unsigned*)&pk_l[rr][0])[dw] = w;
    }
    __syncthreads();

    // A fragments: A[m=colk][k=quad*8+j], k-slices 0/1, hi/lo
    short8 ah0 = *(const short8*)&qh_l[colk][quad * 8];
    short8 ah1 = *(const short8*)&qh_l[colk][32 + quad * 8];
    short8 al0 = *(const short8*)&ql_l[colk][quad * 8];
    short8 al1 = *(const short8*)&ql_l[colk][32 + quad * 8];

    // qrk[r][c] = q[r] . rpe_k[c]  (direct global reads, zero barriers inside)
    for (int c = g; c < 129; c += 16) {
        const float* e = rpe_k + (size_t)c * HDD;
        float a0 = 0.f, a1 = 0.f, a2 = 0.f, a3 = 0.f;
        #pragma unroll
        for (int j4 = 0; j4 < 16; ++j4) {
            float4 q4 = *(const float4*)&qf_l[r16][j4 * 4];
            float4 e4 = *(const float4*)(e + j4 * 4);
            a0 = fmaf(q4.x, e4.x, a0);
            a1 = fmaf(q4.y, e4.y, a1);
            a2 = fmaf(q4.z, e4.z, a2);
            a3 = fmaf(q4.w, e4.w, a3);
        }
        qrk_l[r16][c] = (a0 + a1) + (a2 + a3);
    }
    __syncthreads();

    // ---------------- pass A: zero-barrier MFMA + online stats ----------------
    float s_reg[NCH][4];
    float sm[4], sl[4], sl2[4], sc[4];
    #pragma unroll
    for (int j = 0; j < 4; ++j) { sm[j] = -1e30f; sl[j] = 0.f; sl2[j] = 0.f; sc[j] = 0.f; }
    const int myk = wv * 16 + colk;     // key offset within chunk, 0..63

    #pragma unroll
    for (int cc = 0; cc < NCH; ++cc) {
        const int key = cc * CH + myk;
        const int krow = (key < KLL) ? key : 0;
        const size_t ko = ((size_t)n * KLL + krow) * HDD;
        short8 bh0 = *(const short8*)(kh_g + ko + quad * 8);
        short8 bh1 = *(const short8*)(kh_g + ko + 32 + quad * 8);
        short8 bl0 = *(const short8*)(kl_g + ko + quad * 8);
        short8 bl1 = *(const short8*)(kl_g + ko + 32 + quad * 8);
        f32x4 c4 = {0.f, 0.f, 0.f, 0.f};
        c4 = __builtin_amdgcn_mfma_f32_16x16x32_bf16(ah0, bh0, c4, 0, 0, 0);
        c4 = __builtin_amdgcn_mfma_f32_16x16x32_bf16(ah1, bh1, c4, 0, 0, 0);
        c4 = __builtin_amdgcn_mfma_f32_16x16x32_bf16(ah0, bl0, c4, 0, 0, 0);
        c4 = __builtin_amdgcn_mfma_f32_16x16x32_bf16(ah1, bl1, c4, 0, 0, 0);
        c4 = __builtin_amdgcn_mfma_f32_16x16x32_bf16(al0, bh0, c4, 0, 0, 0);
        c4 = __builtin_amdgcn_mfma_f32_16x16x32_bf16(al1, bh1, c4, 0, 0, 0);

        #pragma unroll
        for (int reg = 0; reg < 4; ++reg) {
            const int row = quad * 4 + reg;
            float s = -1e30f;
            if (key < klen && row < rows) {
                int rid = pk_l[row][key];
                if (rid != 255) {
                    s = c4[reg] + qrk_l[row][rid];
                    sc[reg] += 1.f;
                    if (s <= sm[reg]) {
                        float e = expf(s - sm[reg]);
                        sl[reg] += e; sl2[reg] = fmaf(e, e, sl2[reg]);
                    } else {
                        float e = expf(sm[reg] - s);
                        sl[reg] = fmaf(sl[reg], e, 1.f);
                        sl2[reg] = fmaf(sl2[reg], e * e, 1.f);
                        sm[reg] = s;
                    }
                }
            }
            s_reg[cc][reg] = s;
        }
    }

    // merge stats: 16 lanes within quad, then across 4 waves
    #pragma unroll
    for (int reg = 0; reg < 4; ++reg) {
        #pragma unroll
        for (int d = 1; d < 16; d <<= 1) {
            float mo = __shfl_xor(sm[reg], d, 16);
            float lo = __shfl_xor(sl[reg], d, 16);
            float l2o = __shfl_xor(sl2[reg], d, 16);
            float co = __shfl_xor(sc[reg], d, 16);
            float mn = fmaxf(sm[reg], mo);
            float ea = expf(sm[reg] - mn), eb = expf(mo - mn);
            sl[reg] = sl[reg] * ea + lo * eb;
            sl2[reg] = sl2[reg] * ea * ea + l2o * eb * eb;
            sm[reg] = mn; sc[reg] += co;
        }
    }
    if (colk == 0) {
        #pragma unroll
        for (int reg = 0; reg < 4; ++reg)
            stats_l[wv][quad * 4 + reg] = make_float4(sm[reg], sl[reg], sl2[reg], sc[reg]);
    }
    __syncthreads();
    if (tid < TB) {
        float M = -1e30f, L = 0.f, L2 = 0.f, C = 0.f;
        #pragma unroll
        for (int w = 0; w < 4; ++w) {
            float4 s4 = stats_l[w][tid];
            float mn = fmaxf(M, s4.x);
            float ea = expf(M - mn), eb = expf(s4.x - mn);
            L = L * ea + s4.y * eb;
            L2 = L2 * ea * ea + s4.z * eb * eb;
            M = mn; C += s4.w;
        }
        float inv = (L > 0.f) ? 1.f / L : 0.f;
        float mean = 1.f / (C + 1e-8f);     // key_sum == 1
        float sump2 = L2 * inv * inv;
        float var = (sump2 - 2.f * mean + C * mean * mean) / (C - 1.f + 1e-8f);
        var = fmaxf(var, 0.f);
        float thr = mean - 0.5f * sqrtf(var);
        stats_l[0][tid] = make_float4(M, inv, thr, 0.f);
    }
    // zero pr (reuses qrk_l — qrk values are already folded into s_reg)
    for (int i = tid; i < TB * 132; i += 256) ((float*)qrk_l)[i] = 0.f;
    __syncthreads();

    // ---------------- pass B: exp + threshold + PV (no K traffic) ----------------
    float st_m[4], st_inv[4], st_thr[4];
    #pragma unroll
    for (int reg = 0; reg < 4; ++reg) {
        float4 s4 = stats_l[0][quad * 4 + reg];
        st_m[reg] = s4.x; st_inv[reg] = s4.y; st_thr[reg] = s4.z;
    }
    float sig[4] = {0.f, 0.f, 0.f, 0.f};
    float4 acc = {0.f, 0.f, 0.f, 0.f};

    #pragma unroll
    for (int cc = 0; cc < NCH; ++cc) {
        const int key = cc * CH + myk;
        #pragma unroll
        for (int reg = 0; reg < 4; ++reg) {
            const int row = quad * 4 + reg;
            const float s = s_reg[cc][reg];
            float p = 0.f;
            if (s > -1e29f) {                  // valid row, unmasked, key < klen
                p = expf(s - st_m[reg]) * st_inv[reg];
                if (p < st_thr[reg]) p = 0.f;
                if (p > 0.f) {
                    sig[reg] += p;
                    int rid = pk_l[row][key];
                    atomicAdd(&qrk_l[row][rid], p);
                }
            }
            qf_l[row][myk] = p;     // p_ch
        }
        __syncthreads();
        const int base = cc * CH;
        #pragma unroll 4
        for (int kk = 0; kk < CH; ++kk) {
            float p = qf_l[r16][kk];
            if (p != 0.f) {
                float4 v4 = *(const float4*)(v_s + ((size_t)n * KLL + base + kk) * HDD + g * 4);
                acc.x = fmaf(p, v4.x, acc.x);
                acc.y = fmaf(p, v4.y, acc.y);
                acc.z = fmaf(p, v4.z, acc.z);
                acc.w = fmaf(p, v4.w, acc.w);
            }
        }
        __syncthreads();
    }

    // survivor-sum reduce
    #pragma unroll
    for (int reg = 0; reg < 4; ++reg) {
        #pragma unroll
        for (int d = 1; d < 16; d <<= 1) sig[reg] += __shfl_xor(sig[reg], d, 16);
    }
    if (colk == 0) {
        #pragma unroll
        for (int reg = 0; reg < 4; ++reg)
            stats_l[wv][quad * 4 + reg] = make_float4(sig[reg], 0.f, 0.f, 0.f);
    }
    __syncthreads();
    if (tid < TB) {
        float s = stats_l[0][tid].x + stats_l[1][tid].x + stats_l[2][tid].x + stats_l[3][tid].x;
        stats_l[0][tid].y = (s > 0.f) ? 1.f / s : 0.f;
    }
    __syncthreads();

    if (r16 < rows) {
        float4 ar = {0.f, 0.f, 0.f, 0.f};
        for (int c = 0; c < 129; ++c) {
            float p = qrk_l[r16][c];
            if (p != 0.f) {
                float4 v4 = *(const float4*)(rpe_v + (size_t)c * HDD + g * 4);
                ar.x = fmaf(p, v4.x, ar.x);
                ar.y = fmaf(p, v4.y, ar.y);
                ar.z = fmaf(p, v4.z, ar.z);
                ar.w = fmaf(p, v4.w, ar.w);
            }
        }
        const float invS = stats_l[0][r16].y;
        float4 o;
        o.x = (2.f * acc.x + ar.x) * invS;
        o.y = (2.f * acc.y + ar.y) * invS;
        o.z = (2.f * acc.z + ar.z) * invS;
        o.w = (2.f * acc.w + ar.w) * invS;
        *(float4*)(attn_buf + ((size_t)(t0 + r16) * BB + b) * DD + h * HDD + g * 4) = o;
    }
}

__global__ __launch_bounds__(256)
void out_proj_kernel(const float* __restrict__ attn_buf,
                     const float* __restrict__ wo,
                     const float* __restrict__ bo,
                     float* __restrict__ out)
{
    __shared__ float As[16][65];
    __shared__ float Ws[16][65];
    const int tid = threadIdx.x;
    const int m0 = blockIdx.x * 64;
    const int n0 = blockIdx.y * 64;
    const int tx = tid & 15;
    const int ty = tid >> 4;
    float acc[4][4] = {};

    for (int k0 = 0; k0 < DD; k0 += 16) {
        #pragma unroll
        for (int i = 0; i < 4; ++i) {
            int idx = tid + i * 256;
            int kk = idx & 15;
            int mm = idx >> 4;
            int m = m0 + mm;
            As[kk][mm] = (m < NROWS) ? attn_buf[(size_t)m * DD + k0 + kk] : 0.f;
            Ws[kk][mm] = wo[(size_t)(n0 + mm) * DD + k0 + kk];
        }
        __syncthreads();
        #pragma unroll
        for (int kk = 0; kk < 16; ++kk) {
            float a[4], wv[4];
            #pragma unroll
            for (int i = 0; i < 4; ++i) a[i] = As[kk][ty * 4 + i];
            #pragma unroll
            for (int j = 0; j < 4; ++j) wv[j] = Ws[kk][tx * 4 + j];
            #pragma unroll
            for (int i = 0; i < 4; ++i)
                #pragma unroll
                for (int j = 0; j < 4; ++j)
                    acc[i][j] = fmaf(a[i], wv[j], acc[i][j]);
        }
        __syncthreads();
    }

    #pragma unroll
    for (int i = 0; i < 4; ++i) {
        int m = m0 + ty * 4 + i;
        if (m >= NROWS) continue;
        int row = m >> 3;
        #pragma unroll
        for (int j = 0; j < 4; ++j) {
            int n = n0 + tx * 4 + j;
            float v = acc[i][j] + bo[n];
            if (row >= TQ - MMEM) v = tanhf(v);
            out[(size_t)m * DD + n] = v;
        }
    }
}

extern "C" void kernel_launch(void* const* d_in, const int* in_sizes, int n_in,
                              void* d_out, int out_size, void* d_ws, size_t ws_size,
                              hipStream_t stream) {
    const float*          x      = (const float*)d_in[0];
    const int*            lengths= (const int*)d_in[1];
    const float*          mems   = (const float*)d_in[2];
    const void*           amask  = (const void*)d_in[3];
    const int*            rpe    = (const int*)d_in[4];
    const float*          wq     = (const float*)d_in[6];
    const float*          bq     = (const float*)d_in[7];
    const float*          wkv    = (const float*)d_in[8];
    const float*          bkv    = (const float*)d_in[9];
    const float*          wo     = (const float*)d_in[10];
    const float*          bo     = (const float*)d_in[11];
    const float*          rpe_k  = (const float*)d_in[12];
    const float*          rpe_v  = (const float*)d_in[13];

    const size_t NE = (size_t)NHEADS * KLL * HDD;   // 3,268,608
    float* ws       = (float*)d_ws;
    float* q_s      = ws;
    float* v_s      = ws + NE;
    float* attn_buf = ws + 2 * NE;
    unsigned short* k_hi = (unsigned short*)(ws + 3 * NE);
    unsigned short* k_lo = k_hi + NE;
    unsigned char*  pk   = (unsigned char*)(k_hi + 2 * NE);
    int*   mmode    = (int*)(pk + (size_t)TT * 800);

    detect_mask_kernel<<<1, 1024, 0, stream>>>((const unsigned int*)amask, mmode);
    pack_kernel<<<(TT * 200 + 255) / 256, 256, 0, stream>>>(amask, rpe, mmode, (unsigned int*)pk);
    proj_kernel<0><<<dim3(100, 8),  256, 0, stream>>>(x, mems, wq,  bq,  q_s, k_hi, k_lo, v_s);
    proj_kernel<1><<<dim3(100, 16), 256, 0, stream>>>(x, mems, wkv, bkv, q_s, k_hi, k_lo, v_s);
    attn_kernel<<<dim3(50, NHEADS), 256, 0, stream>>>(q_s, k_hi, k_lo, v_s, lengths, pk,
                                                      rpe_k, rpe_v, attn_buf);
    out_proj_kernel<<<dim3(100, 8), 256, 0, stream>>>(attn_buf, wo, bo, (float*)d_out);
}

// Round 10
// 837.831 us; speedup vs baseline: 1.7469x; 1.7469x over previous
//
#include <hip/hip_runtime.h>
#include <hip/hip_bf16.h>
#include <math.h>

// Problem constants (fixed by the reference)
#define TT   799
#define BB   8
#define DD   512
#define HH   8
#define HDD  64
#define MMEM 6
#define RRCB 24
#define KLL  798
#define TQ   798            // query rows actually needed (row 798 unused)
#define NROWS (TQ * BB)     // 6384
#define NHEADS 64           // B*H
#define NEG_INF (-INFINITY)

#define TB   16             // t-rows per attention block
#define CH   64             // keys per MFMA chunk
#define NCH  13             // 13*64 = 832 >= 798
#define VTS  832            // v_t row stride in keys (covers chunk 12 fully)

static_assert(NROWS == 6384, "");

typedef __attribute__((ext_vector_type(8))) short short8;
typedef __attribute__((ext_vector_type(4))) float f32x4;

__device__ __forceinline__ unsigned short f2bf(float x) {
    union { float f; unsigned u; } c; c.f = x;
    unsigned r = c.u + 0x7FFFu + ((c.u >> 16) & 1u);   // RNE
    return (unsigned short)(r >> 16);
}
__device__ __forceinline__ float bf2f(unsigned short b) {
    union { unsigned u; float f; } c; c.u = ((unsigned)b) << 16; return c.f;
}

// mode 0 = int32 (0/1), mode 1 = float32 (0.0/1.0), mode 2 = uint8 bool.
__global__ void detect_mask_kernel(const unsigned int* __restrict__ a,
                                   int* __restrict__ mode)
{
    __shared__ int c0s, cHs;
    if (threadIdx.x == 0) { c0s = 0; cHs = 0; }
    __syncthreads();
    int c0 = 0, cH = 0;
    const int ND = 4096;
    for (int i = threadIdx.x; i < ND; i += blockDim.x) {
        unsigned int w = a[i];
        if (w & 0x000000FFu) c0++;
        if (w & 0xFFFFFF00u) cH++;
    }
    atomicAdd(&c0s, c0); atomicAdd(&cHs, cH);
    __syncthreads();
    if (threadIdx.x == 0)
        *mode = (cHs == 0) ? 0 : ((c0s == 0) ? 1 : 2);
}

// Pack (mask, rpe) -> byte: rid 0..128 if unmasked, 255 if masked. Row stride 800.
__global__ __launch_bounds__(256)
void pack_kernel(const void* __restrict__ amask,
                 const int* __restrict__ rpe,
                 const int* __restrict__ mode_p,
                 unsigned int* __restrict__ pk)
{
    const int mode = *mode_p;
    const int NW = TT * 200;
    int i = blockIdx.x * 256 + threadIdx.x;
    if (i >= NW) return;
    int t = i / 200;
    int kbase = (i - t * 200) * 4;
    unsigned out = 0;
    #pragma unroll
    for (int u = 0; u < 4; ++u) {
        int k = kbase + u;
        unsigned byte = 255u;
        if (k < KLL) {
            size_t idx = (size_t)t * KLL + k;
            bool masked;
            if (mode == 0)      masked = (((const int*)amask)[idx] != 0);
            else if (mode == 1) masked = (((const float*)amask)[idx] != 0.f);
            else                masked = (((const unsigned char*)amask)[idx] != 0);
            byte = masked ? 255u : (unsigned)rpe[idx];
        }
        out |= byte << (8 * u);
    }
    pk[i] = out;
}

// rpe_k f32[129][64] -> bf16 hi/lo [144][64] (rows 129..143 zero)
__global__ __launch_bounds__(256)
void rpe_prep_kernel(const float* __restrict__ rpe_k,
                     unsigned short* __restrict__ rk_hi,
                     unsigned short* __restrict__ rk_lo)
{
    int i = blockIdx.x * 256 + threadIdx.x;
    if (i >= 144 * 64) return;
    int c = i >> 6;
    float v = (c < 129) ? rpe_k[i] : 0.f;
    unsigned short hi = f2bf(v);
    rk_hi[i] = hi;
    rk_lo[i] = f2bf(v - bf2f(hi));
}

// v row-major bf16 hi/lo [head][key][hd] -> v_t [head][hd][VTS] (keys 798..831 zero)
__global__ __launch_bounds__(256)
void transpose_v_kernel(const unsigned short* __restrict__ vr_hi,
                        const unsigned short* __restrict__ vr_lo,
                        unsigned short* __restrict__ vt_hi,
                        unsigned short* __restrict__ vt_lo)
{
    const int head = blockIdx.y;
    const int kb = blockIdx.x * 64;
    __shared__ unsigned short th[64][66];
    __shared__ unsigned short tl[64][66];
    const int tid = threadIdx.x;
    for (int i = tid; i < 64 * 64; i += 256) {
        int ky = i >> 6, hd = i & 63;
        int key = kb + ky;
        unsigned short hv = 0, lv = 0;
        if (key < KLL) {
            size_t o = ((size_t)head * KLL + key) * HDD + hd;
            hv = vr_hi[o]; lv = vr_lo[o];
        }
        th[ky][hd] = hv; tl[ky][hd] = lv;
    }
    __syncthreads();
    for (int i = tid; i < 64 * 64; i += 256) {
        int hd = i >> 6, ky = i & 63;
        size_t o = ((size_t)head * HDD + hd) * VTS + kb + ky;
        vt_hi[o] = th[ky][hd];
        vt_lo[o] = tl[ky][hd];
    }
}

// MODE 0: q = x @ wq^T + bq (scaled, f32). MODE 1: k -> bf16 hi/lo, v -> bf16 hi/lo row-major
template<int MODE>
__global__ __launch_bounds__(256)
void proj_kernel(const float* __restrict__ x,
                 const float* __restrict__ mems,
                 const float* __restrict__ w,
                 const float* __restrict__ bias,
                 float* __restrict__ q_s,
                 unsigned short* __restrict__ k_hi,
                 unsigned short* __restrict__ k_lo,
                 unsigned short* __restrict__ vr_hi,
                 unsigned short* __restrict__ vr_lo)
{
    __shared__ float As[16][65];
    __shared__ float Ws[16][65];
    const int tid = threadIdx.x;
    const int m0 = blockIdx.x * 64;
    const int n0 = blockIdx.y * 64;
    const int tx = tid & 15;
    const int ty = tid >> 4;
    float acc[4][4] = {};

    for (int k0 = 0; k0 < DD; k0 += 16) {
        #pragma unroll
        for (int i = 0; i < 4; ++i) {
            int idx = tid + i * 256;
            int kk = idx & 15;
            int mm = idx >> 4;
            int m = m0 + mm;
            float va = 0.f;
            if (m < NROWS) {
                int row = m >> 3, b = m & 7;
                const float* src;
                if (MODE == 0) src = x + ((size_t)row * BB + b) * DD;
                else src = (row < MMEM) ? (mems + ((size_t)row * BB + b) * DD)
                                        : (x + ((size_t)(row - MMEM) * BB + b) * DD);
                va = src[k0 + kk];
            }
            As[kk][mm] = va;
            int n = n0 + mm;
            Ws[kk][mm] = w[(size_t)n * DD + k0 + kk];
        }
        __syncthreads();
        #pragma unroll
        for (int kk = 0; kk < 16; ++kk) {
            float a[4], wv[4];
            #pragma unroll
            for (int i = 0; i < 4; ++i) a[i] = As[kk][ty * 4 + i];
            #pragma unroll
            for (int j = 0; j < 4; ++j) wv[j] = Ws[kk][tx * 4 + j];
            #pragma unroll
            for (int i = 0; i < 4; ++i)
                #pragma unroll
                for (int j = 0; j < 4; ++j)
                    acc[i][j] = fmaf(a[i], wv[j], acc[i][j]);
        }
        __syncthreads();
    }

    #pragma unroll
    for (int i = 0; i < 4; ++i) {
        int m = m0 + ty * 4 + i;
        if (m >= NROWS) continue;
        int row = m >> 3, b = m & 7;
        #pragma unroll
        for (int j = 0; j < 4; ++j) {
            int n = n0 + tx * 4 + j;
            float v = acc[i][j] + bias[n];
            if (MODE == 0) {
                int h = n >> 6, hd = n & 63;
                q_s[((size_t)(b * HH + h) * TQ + row) * HDD + hd] = v * 0.125f;
            } else {
                if (n < DD) {
                    int h = n >> 6, hd = n & 63;
                    size_t o = ((size_t)(b * HH + h) * KLL + row) * HDD + hd;
                    unsigned short hi = f2bf(v);
                    k_hi[o] = hi;
                    k_lo[o] = f2bf(v - bf2f(hi));
                } else {
                    int n2 = n - DD;
                    int h = n2 >> 6, hd = n2 & 63;
                    size_t o = ((size_t)(b * HH + h) * KLL + row) * HDD + hd;
                    unsigned short hi = f2bf(v);
                    vr_hi[o] = hi;
                    vr_lo[o] = f2bf(v - bf2f(hi));
                }
            }
        }
    }
}

union ULds {
    unsigned char pk[TB][800];                                   // 12800 B (pass A)
    struct { unsigned short hi[2][TB][72]; unsigned short lo[2][TB][72]; } p;  // 9216 B (pass B)
};

// Attention v6: all-MFMA. qrk via MFMA, QK^T pass A (no barriers, two-sweep
// stats, e cached in regs), PV via MFMA (P tile LDS double-buffered, V^T
// direct-global A-frags). rid bytes cached in regs so pk LDS unions with P.
__global__ __launch_bounds__(256, 4)
void attn_kernel(const float* __restrict__ q_s,
                 const unsigned short* __restrict__ kh_g,
                 const unsigned short* __restrict__ kl_g,
                 const unsigned short* __restrict__ vt_hi,
                 const unsigned short* __restrict__ vt_lo,
                 const int* __restrict__ lengths,
                 const unsigned char* __restrict__ pk,
                 const unsigned short* __restrict__ rk_hi,
                 const unsigned short* __restrict__ rk_lo,
                 const float* __restrict__ rpe_v,
                 float* __restrict__ attn_buf)
{
    const int t0 = blockIdx.x * TB;
    const int rows = min(TB, TQ - t0);
    const int n = blockIdx.y;
    const int b = n >> 3;
    const int h = n & 7;
    const int tid = threadIdx.x;
    const int wv = tid >> 6;
    const int quad = (tid >> 4) & 3;
    const int colk = tid & 15;
    const int myk = wv * 16 + colk;

    __shared__ unsigned short qh_l[TB][72];
    __shared__ unsigned short ql_l[TB][72];
    __shared__ float qrk_l[TB][132];        // qrk, then pr buckets
    __shared__ ULds u;
    __shared__ float4 stats_l[4][TB];

    const int klen = lengths[b] + MMEM + RRCB;

    // phase 0: q bf16 hi/lo + pk tile -> LDS
    for (int i = tid; i < TB * 16; i += 256) {
        int rr = i >> 4, j4 = i & 15;
        float4 v = {0.f, 0.f, 0.f, 0.f};
        if (rr < rows) v = *(const float4*)(q_s + ((size_t)n * TQ + t0 + rr) * HDD + j4 * 4);
        unsigned short h0 = f2bf(v.x), h1 = f2bf(v.y), h2 = f2bf(v.z), h3 = f2bf(v.w);
        qh_l[rr][j4 * 4 + 0] = h0; qh_l[rr][j4 * 4 + 1] = h1;
        qh_l[rr][j4 * 4 + 2] = h2; qh_l[rr][j4 * 4 + 3] = h3;
        ql_l[rr][j4 * 4 + 0] = f2bf(v.x - bf2f(h0));
        ql_l[rr][j4 * 4 + 1] = f2bf(v.y - bf2f(h1));
        ql_l[rr][j4 * 4 + 2] = f2bf(v.z - bf2f(h2));
        ql_l[rr][j4 * 4 + 3] = f2bf(v.w - bf2f(h3));
    }
    for (int i = tid; i < TB * 200; i += 256) {
        int rr = i / 200, dw = i - rr * 200;
        unsigned w = 0xFFFFFFFFu;
        if (rr < rows) w = ((const unsigned*)pk)[(t0 + rr) * 200 + dw];
        ((unsigned*)&u.pk[rr][0])[dw] = w;
    }
    __syncthreads();

    // A fragments (Q), held in regs all kernel
    short8 ah0 = *(const short8*)&qh_l[colk][quad * 8];
    short8 ah1 = *(const short8*)&qh_l[colk][32 + quad * 8];
    short8 al0 = *(const short8*)&ql_l[colk][quad * 8];
    short8 al1 = *(const short8*)&ql_l[colk][32 + quad * 8];

    // qrk via MFMA: n-tiles of rpe_k rows; wave wv does tiles wv, wv+4, wv+8
    for (int t = wv; t < 9; t += 4) {
        const size_t rb = (size_t)(t * 16 + colk) * 64;
        short8 bh0 = *(const short8*)(rk_hi + rb + quad * 8);
        short8 bh1 = *(const short8*)(rk_hi + rb + 32 + quad * 8);
        short8 bl0 = *(const short8*)(rk_lo + rb + quad * 8);
        short8 bl1 = *(const short8*)(rk_lo + rb + 32 + quad * 8);
        f32x4 c4 = {0.f, 0.f, 0.f, 0.f};
        c4 = __builtin_amdgcn_mfma_f32_16x16x32_bf16(ah0, bh0, c4, 0, 0, 0);
        c4 = __builtin_amdgcn_mfma_f32_16x16x32_bf16(ah1, bh1, c4, 0, 0, 0);
        c4 = __builtin_amdgcn_mfma_f32_16x16x32_bf16(ah0, bl0, c4, 0, 0, 0);
        c4 = __builtin_amdgcn_mfma_f32_16x16x32_bf16(ah1, bl1, c4, 0, 0, 0);
        c4 = __builtin_amdgcn_mfma_f32_16x16x32_bf16(al0, bh0, c4, 0, 0, 0);
        c4 = __builtin_amdgcn_mfma_f32_16x16x32_bf16(al1, bh1, c4, 0, 0, 0);
        int c = t * 16 + colk;
        if (c <= 128) {
            #pragma unroll
            for (int reg = 0; reg < 4; ++reg) qrk_l[quad * 4 + reg][c] = c4[reg];
        }
    }
    __syncthreads();

    // ---- pass A: QK^T MFMA, record scores + max (no exp, no barriers) ----
    float s_reg[NCH][4];
    unsigned rid_pack[NCH];
    float mx[4] = {-1e30f, -1e30f, -1e30f, -1e30f};

    #pragma unroll
    for (int cc = 0; cc < NCH; ++cc) {
        const int key = cc * CH + myk;
        const int krow = min(key, KLL - 1);
        const size_t ko = ((size_t)n * KLL + krow) * HDD;
        short8 bh0 = *(const short8*)(kh_g + ko + quad * 8);
        short8 bh1 = *(const short8*)(kh_g + ko + 32 + quad * 8);
        short8 bl0 = *(const short8*)(kl_g + ko + quad * 8);
        short8 bl1 = *(const short8*)(kl_g + ko + 32 + quad * 8);
        f32x4 c4 = {0.f, 0.f, 0.f, 0.f};
        c4 = __builtin_amdgcn_mfma_f32_16x16x32_bf16(ah0, bh0, c4, 0, 0, 0);
        c4 = __builtin_amdgcn_mfma_f32_16x16x32_bf16(ah1, bh1, c4, 0, 0, 0);
        c4 = __builtin_amdgcn_mfma_f32_16x16x32_bf16(ah0, bl0, c4, 0, 0, 0);
        c4 = __builtin_amdgcn_mfma_f32_16x16x32_bf16(ah1, bl1, c4, 0, 0, 0);
        c4 = __builtin_amdgcn_mfma_f32_16x16x32_bf16(al0, bh0, c4, 0, 0, 0);
        c4 = __builtin_amdgcn_mfma_f32_16x16x32_bf16(al1, bh1, c4, 0, 0, 0);

        const bool vkey = (key < klen);
        unsigned rpack = 0;
        #pragma unroll
        for (int reg = 0; reg < 4; ++reg) {
            const int row = quad * 4 + reg;
            float s = -1e30f;
            unsigned rid = 255u;
            if (vkey && row < rows) {
                rid = u.pk[row][key];
                if (rid != 255u) s = c4[reg] + qrk_l[row][rid];
            }
            rpack |= rid << (8 * reg);
            mx[reg] = fmaxf(mx[reg], s);
            s_reg[cc][reg] = s;
        }
        rid_pack[cc] = rpack;
    }

    // max merge: shfl16 then cross-wave
    #pragma unroll
    for (int reg = 0; reg < 4; ++reg)
        #pragma unroll
        for (int d = 1; d < 16; d <<= 1) mx[reg] = fmaxf(mx[reg], __shfl_xor(mx[reg], d, 16));
    if (colk == 0) {
        #pragma unroll
        for (int reg = 0; reg < 4; ++reg)
            stats_l[wv][quad * 4 + reg] = make_float4(mx[reg], 0.f, 0.f, 0.f);
    }
    __syncthreads();
    if (tid < TB) {
        float M = fmaxf(fmaxf(stats_l[0][tid].x, stats_l[1][tid].x),
                        fmaxf(stats_l[2][tid].x, stats_l[3][tid].x));
        stats_l[0][tid].x = M;
    }
    __syncthreads();

    // e-sweep: e = exp(s - M), overwrite s_reg; accumulate l, l2, count
    float Mr[4], l[4] = {0,0,0,0}, l2[4] = {0,0,0,0}, cn[4] = {0,0,0,0};
    #pragma unroll
    for (int reg = 0; reg < 4; ++reg) Mr[reg] = stats_l[0][quad * 4 + reg].x;
    #pragma unroll
    for (int cc = 0; cc < NCH; ++cc) {
        #pragma unroll
        for (int reg = 0; reg < 4; ++reg) {
            float s = s_reg[cc][reg];
            float e = 0.f;
            if (s > -1e29f) { e = expf(s - Mr[reg]); cn[reg] += 1.f; }
            l[reg] += e;
            l2[reg] = fmaf(e, e, l2[reg]);
            s_reg[cc][reg] = e;
        }
    }
    #pragma unroll
    for (int reg = 0; reg < 4; ++reg)
        #pragma unroll
        for (int d = 1; d < 16; d <<= 1) {
            l[reg]  += __shfl_xor(l[reg], d, 16);
            l2[reg] += __shfl_xor(l2[reg], d, 16);
            cn[reg] += __shfl_xor(cn[reg], d, 16);
        }
    if (colk == 0) {
        #pragma unroll
        for (int reg = 0; reg < 4; ++reg)
            stats_l[wv][quad * 4 + reg] = make_float4(Mr[reg], l[reg], l2[reg], cn[reg]);
    }
    __syncthreads();
    if (tid < TB) {
        float L = 0.f, L2 = 0.f, C = 0.f;
        #pragma unroll
        for (int w = 0; w < 4; ++w) {
            float4 s4 = stats_l[w][tid];
            L += s4.y; L2 += s4.z; C += s4.w;
        }
        float inv = (L > 0.f) ? 1.f / L : 0.f;
        float mean = 1.f / (C + 1e-8f);
        float sump2 = L2 * inv * inv;
        float var = (sump2 - 2.f * mean + C * mean * mean) / (C - 1.f + 1e-8f);
        var = fmaxf(var, 0.f);
        float thr = mean - 0.5f * sqrtf(var);
        stats_l[0][tid] = make_float4(stats_l[0][tid].x, inv, thr, 0.f);
    }
    // zero pr (qrk_l reuse; qrk folded into s_reg already)
    for (int i = tid; i < TB * 132; i += 256) ((float*)qrk_l)[i] = 0.f;
    __syncthreads();

    // ---- pass B: p = e*inv, threshold, buckets, PV via MFMA ----
    float inv_r[4], thr_r[4];
    #pragma unroll
    for (int reg = 0; reg < 4; ++reg) {
        float4 s4 = stats_l[0][quad * 4 + reg];
        inv_r[reg] = s4.y; thr_r[reg] = s4.z;
    }
    float sig[4] = {0.f, 0.f, 0.f, 0.f};
    f32x4 oacc = {0.f, 0.f, 0.f, 0.f};

    auto computeP = [&](int cc, int buf) {
        const unsigned rpack = rid_pack[cc];
        #pragma unroll
        for (int reg = 0; reg < 4; ++reg) {
            const int row = quad * 4 + reg;
            float p = s_reg[cc][reg] * inv_r[reg];
            if (p < thr_r[reg]) p = 0.f;
            if (p > 0.f) {
                sig[reg] += p;
                atomicAdd(&qrk_l[row][(rpack >> (8 * reg)) & 255u], p);
            }
            unsigned short ph = f2bf(p);
            u.p.hi[buf][row][myk] = ph;
            u.p.lo[buf][row][myk] = f2bf(p - bf2f(ph));
        }
    };

    computeP(0, 0);
    __syncthreads();
    for (int cc = 0; cc < NCH; ++cc) {
        const int buf = cc & 1;
        const size_t vbase = ((size_t)n * HDD + wv * 16 + colk) * VTS + cc * CH;
        short8 vh0 = *(const short8*)(vt_hi + vbase + quad * 8);
        short8 vh1 = *(const short8*)(vt_hi + vbase + 32 + quad * 8);
        short8 vl0 = *(const short8*)(vt_lo + vbase + quad * 8);
        short8 vl1 = *(const short8*)(vt_lo + vbase + 32 + quad * 8);
        short8 ph0 = *(const short8*)&u.p.hi[buf][colk][quad * 8];
        short8 ph1 = *(const short8*)&u.p.hi[buf][colk][32 + quad * 8];
        short8 pl0 = *(const short8*)&u.p.lo[buf][colk][quad * 8];
        short8 pl1 = *(const short8*)&u.p.lo[buf][colk][32 + quad * 8];
        oacc = __builtin_amdgcn_mfma_f32_16x16x32_bf16(vh0, ph0, oacc, 0, 0, 0);
        oacc = __builtin_amdgcn_mfma_f32_16x16x32_bf16(vh1, ph1, oacc, 0, 0, 0);
        oacc = __builtin_amdgcn_mfma_f32_16x16x32_bf16(vh0, pl0, oacc, 0, 0, 0);
        oacc = __builtin_amdgcn_mfma_f32_16x16x32_bf16(vh1, pl1, oacc, 0, 0, 0);
        oacc = __builtin_amdgcn_mfma_f32_16x16x32_bf16(vl0, ph0, oacc, 0, 0, 0);
        oacc = __builtin_amdgcn_mfma_f32_16x16x32_bf16(vl1, ph1, oacc, 0, 0, 0);
        if (cc + 1 < NCH) computeP(cc + 1, (cc + 1) & 1);
        __syncthreads();
    }

    // survivor-sum merge
    #pragma unroll
    for (int reg = 0; reg < 4; ++reg)
        #pragma unroll
        for (int d = 1; d < 16; d <<= 1) sig[reg] += __shfl_xor(sig[reg], d, 16);
    if (colk == 0) {
        #pragma unroll
        for (int reg = 0; reg < 4; ++reg)
            stats_l[wv][quad * 4 + reg].w = sig[reg];
    }
    __syncthreads();
    if (tid < TB) {
        float S = stats_l[0][tid].w + stats_l[1][tid].w + stats_l[2][tid].w + stats_l[3][tid].w;
        stats_l[0][tid].w = (S > 0.f) ? 1.f / S : 0.f;
    }
    __syncthreads();

    // output: lane owns O[row=colk][hd = wv*16 + quad*4 + reg]
    if (colk < rows) {
        float4 ar = {0.f, 0.f, 0.f, 0.f};
        const int hdb = wv * 16 + quad * 4;
        for (int c = 0; c < 129; ++c) {
            float p = qrk_l[colk][c];
            if (p != 0.f) {
                float4 v4 = *(const float4*)(rpe_v + (size_t)c * HDD + hdb);
                ar.x = fmaf(p, v4.x, ar.x);
                ar.y = fmaf(p, v4.y, ar.y);
                ar.z = fmaf(p, v4.z, ar.z);
                ar.w = fmaf(p, v4.w, ar.w);
            }
        }
        const float invS = stats_l[0][colk].w;
        float4 o;
        o.x = (2.f * oacc[0] + ar.x) * invS;
        o.y = (2.f * oacc[1] + ar.y) * invS;
        o.z = (2.f * oacc[2] + ar.z) * invS;
        o.w = (2.f * oacc[3] + ar.w) * invS;
        *(float4*)(attn_buf + ((size_t)(t0 + colk) * BB + b) * DD + h * HDD + hdb) = o;
    }
}

__global__ __launch_bounds__(256)
void out_proj_kernel(const float* __restrict__ attn_buf,
                     const float* __restrict__ wo,
                     const float* __restrict__ bo,
                     float* __restrict__ out)
{
    __shared__ float As[16][65];
    __shared__ float Ws[16][65];
    const int tid = threadIdx.x;
    const int m0 = blockIdx.x * 64;
    const int n0 = blockIdx.y * 64;
    const int tx = tid & 15;
    const int ty = tid >> 4;
    float acc[4][4] = {};

    for (int k0 = 0; k0 < DD; k0 += 16) {
        #pragma unroll
        for (int i = 0; i < 4; ++i) {
            int idx = tid + i * 256;
            int kk = idx & 15;
            int mm = idx >> 4;
            int m = m0 + mm;
            As[kk][mm] = (m < NROWS) ? attn_buf[(size_t)m * DD + k0 + kk] : 0.f;
            Ws[kk][mm] = wo[(size_t)(n0 + mm) * DD + k0 + kk];
        }
        __syncthreads();
        #pragma unroll
        for (int kk = 0; kk < 16; ++kk) {
            float a[4], wv[4];
            #pragma unroll
            for (int i = 0; i < 4; ++i) a[i] = As[kk][ty * 4 + i];
            #pragma unroll
            for (int j = 0; j < 4; ++j) wv[j] = Ws[kk][tx * 4 + j];
            #pragma unroll
            for (int i = 0; i < 4; ++i)
                #pragma unroll
                for (int j = 0; j < 4; ++j)
                    acc[i][j] = fmaf(a[i], wv[j], acc[i][j]);
        }
        __syncthreads();
    }

    #pragma unroll
    for (int i = 0; i < 4; ++i) {
        int m = m0 + ty * 4 + i;
        if (m >= NROWS) continue;
        int row = m >> 3;
        #pragma unroll
        for (int j = 0; j < 4; ++j) {
            int n = n0 + tx * 4 + j;
            float v = acc[i][j] + bo[n];
            if (row >= TQ - MMEM) v = tanhf(v);
            out[(size_t)m * DD + n] = v;
        }
    }
}

extern "C" void kernel_launch(void* const* d_in, const int* in_sizes, int n_in,
                              void* d_out, int out_size, void* d_ws, size_t ws_size,
                              hipStream_t stream) {
    const float*          x      = (const float*)d_in[0];
    const int*            lengths= (const int*)d_in[1];
    const float*          mems   = (const float*)d_in[2];
    const void*           amask  = (const void*)d_in[3];
    const int*            rpe    = (const int*)d_in[4];
    const float*          wq     = (const float*)d_in[6];
    const float*          bq     = (const float*)d_in[7];
    const float*          wkv    = (const float*)d_in[8];
    const float*          bkv    = (const float*)d_in[9];
    const float*          wo     = (const float*)d_in[10];
    const float*          bo     = (const float*)d_in[11];
    const float*          rpe_k  = (const float*)d_in[12];
    const float*          rpe_v  = (const float*)d_in[13];

    const size_t NE = (size_t)NHEADS * KLL * HDD;   // 3,268,608
    char* p = (char*)d_ws;
    float* q_s = (float*)p;                      p += NE * 4;
    float* attn_buf = (float*)p;                 // aliases v row-major temp (dead before attn writes)
    unsigned short* vr_hi = (unsigned short*)p;
    unsigned short* vr_lo = vr_hi + NE;          p += NE * 4;
    unsigned short* k_hi = (unsigned short*)p;   p += NE * 2;
    unsigned short* k_lo = (unsigned short*)p;   p += NE * 2;
    unsigned short* vt_hi = (unsigned short*)p;  p += (size_t)NHEADS * HDD * VTS * 2;
    unsigned short* vt_lo = (unsigned short*)p;  p += (size_t)NHEADS * HDD * VTS * 2;
    unsigned short* rk_hi = (unsigned short*)p;  p += 144 * 64 * 2;
    unsigned short* rk_lo = (unsigned short*)p;  p += 144 * 64 * 2;
    unsigned char*  pk    = (unsigned char*)p;   p += (size_t)TT * 800;
    int* mmode = (int*)p;

    detect_mask_kernel<<<1, 1024, 0, stream>>>((const unsigned int*)amask, mmode);
    pack_kernel<<<(TT * 200 + 255) / 256, 256, 0, stream>>>(amask, rpe, mmode, (unsigned int*)pk);
    rpe_prep_kernel<<<36, 256, 0, stream>>>(rpe_k, rk_hi, rk_lo);
    proj_kernel<0><<<dim3(100, 8),  256, 0, stream>>>(x, mems, wq,  bq,  q_s, k_hi, k_lo, vr_hi, vr_lo);
    proj_kernel<1><<<dim3(100, 16), 256, 0, stream>>>(x, mems, wkv, bkv, q_s, k_hi, k_lo, vr_hi, vr_lo);
    transpose_v_kernel<<<dim3(13, NHEADS), 256, 0, stream>>>(vr_hi, vr_lo, vt_hi, vt_lo);
    attn_kernel<<<dim3(50, NHEADS), 256, 0, stream>>>(q_s, k_hi, k_lo, vt_hi, vt_lo, lengths, pk,
                                                      rk_hi, rk_lo, rpe_v, attn_buf);
    out_proj_kernel<<<dim3(100, 8), 256, 0, stream>>>(attn_buf, wo, bo, (float*)d_out);
}

// Round 11
// 774.462 us; speedup vs baseline: 1.8898x; 1.0818x over previous
//
#include <hip/hip_runtime.h>
#include <hip/hip_bf16.h>
#include <math.h>

// Problem constants (fixed by the reference)
#define TT   799
#define BB   8
#define DD   512
#define HH   8
#define HDD  64
#define MMEM 6
#define RRCB 24
#define KLL  798
#define TQ   798            // query rows actually needed (row 798 unused)
#define NROWS (TQ * BB)     // 6384
#define NHEADS 64           // B*H
#define NEG_INF (-INFINITY)

#define TB   16             // t-rows per attention block
#define CH   64             // keys per MFMA chunk
#define NCH  13             // 13*64 = 832 >= 798
#define VTS  832            // v_t row stride in keys

static_assert(NROWS == 6384, "");

typedef __attribute__((ext_vector_type(8))) short short8;
typedef __attribute__((ext_vector_type(4))) float f32x4;

__device__ __forceinline__ unsigned short f2bf(float x) {
    union { float f; unsigned u; } c; c.f = x;
    unsigned r = c.u + 0x7FFFu + ((c.u >> 16) & 1u);   // RNE
    return (unsigned short)(r >> 16);
}
__device__ __forceinline__ float bf2f(unsigned short b) {
    union { unsigned u; float f; } c; c.u = ((unsigned)b) << 16; return c.f;
}

// mode 0 = int32 (0/1), mode 1 = float32 (0.0/1.0), mode 2 = uint8 bool.
__global__ void detect_mask_kernel(const unsigned int* __restrict__ a,
                                   int* __restrict__ mode)
{
    __shared__ int c0s, cHs;
    if (threadIdx.x == 0) { c0s = 0; cHs = 0; }
    __syncthreads();
    int c0 = 0, cH = 0;
    const int ND = 4096;
    for (int i = threadIdx.x; i < ND; i += blockDim.x) {
        unsigned int w = a[i];
        if (w & 0x000000FFu) c0++;
        if (w & 0xFFFFFF00u) cH++;
    }
    atomicAdd(&c0s, c0); atomicAdd(&cHs, cH);
    __syncthreads();
    if (threadIdx.x == 0)
        *mode = (cHs == 0) ? 0 : ((c0s == 0) ? 1 : 2);
}

// Pack (mask, rpe) -> byte: rid 0..128 if unmasked, 255 if masked. Row stride 800.
__global__ __launch_bounds__(256)
void pack_kernel(const void* __restrict__ amask,
                 const int* __restrict__ rpe,
                 const int* __restrict__ mode_p,
                 unsigned int* __restrict__ pk)
{
    const int mode = *mode_p;
    const int NW = TT * 200;
    int i = blockIdx.x * 256 + threadIdx.x;
    if (i >= NW) return;
    int t = i / 200;
    int kbase = (i - t * 200) * 4;
    unsigned out = 0;
    #pragma unroll
    for (int u = 0; u < 4; ++u) {
        int k = kbase + u;
        unsigned byte = 255u;
        if (k < KLL) {
            size_t idx = (size_t)t * KLL + k;
            bool masked;
            if (mode == 0)      masked = (((const int*)amask)[idx] != 0);
            else if (mode == 1) masked = (((const float*)amask)[idx] != 0.f);
            else                masked = (((const unsigned char*)amask)[idx] != 0);
            byte = masked ? 255u : (unsigned)rpe[idx];
        }
        out |= byte << (8 * u);
    }
    pk[i] = out;
}

// rpe_k f32[129][64] -> bf16 hi/lo [144][64] (rows 129..143 zero)
__global__ __launch_bounds__(256)
void rpe_prep_kernel(const float* __restrict__ rpe_k,
                     unsigned short* __restrict__ rk_hi,
                     unsigned short* __restrict__ rk_lo)
{
    int i = blockIdx.x * 256 + threadIdx.x;
    if (i >= 144 * 64) return;
    int c = i >> 6;
    float v = (c < 129) ? rpe_k[i] : 0.f;
    unsigned short hi = f2bf(v);
    rk_hi[i] = hi;
    rk_lo[i] = f2bf(v - bf2f(hi));
}

// Split x / mems / weights into bf16 hi/lo
__global__ __launch_bounds__(256)
void split_kernel(const float* __restrict__ x,
                  const float* __restrict__ mems,
                  const float* __restrict__ wq,
                  const float* __restrict__ wkv,
                  const float* __restrict__ wo,
                  unsigned short* __restrict__ xs_hi, unsigned short* __restrict__ xs_lo,
                  unsigned short* __restrict__ ms_hi, unsigned short* __restrict__ ms_lo,
                  unsigned short* __restrict__ w_hi,  unsigned short* __restrict__ w_lo)
{
    const size_t NX = (size_t)NROWS * DD;
    const size_t NM = 48 * DD;
    const size_t NW = 2048 * DD;
    size_t i = (size_t)blockIdx.x * 256 + threadIdx.x;
    float v; unsigned short *dh, *dl; size_t o;
    if (i < NX) { o = i; v = x[o]; dh = xs_hi; dl = xs_lo; }
    else if (i < NX + NM) { o = i - NX; v = mems[o]; dh = ms_hi; dl = ms_lo; }
    else if (i < NX + NM + NW) {
        o = i - NX - NM;
        size_t r = o >> 9;
        if (r < 512) v = wq[o];
        else if (r < 1536) v = wkv[o - (size_t)512 * DD];
        else v = wo[o - (size_t)1536 * DD];
        dh = w_hi; dl = w_lo;
    } else return;
    unsigned short hi = f2bf(v);
    dh[o] = hi;
    dl[o] = f2bf(v - bf2f(hi));
}

// v row-major bf16 hi/lo [head][key][hd] -> v_t [head][hd][VTS] (keys 798..831 zero)
__global__ __launch_bounds__(256)
void transpose_v_kernel(const unsigned short* __restrict__ vr_hi,
                        const unsigned short* __restrict__ vr_lo,
                        unsigned short* __restrict__ vt_hi,
                        unsigned short* __restrict__ vt_lo)
{
    const int head = blockIdx.y;
    const int kb = blockIdx.x * 64;
    __shared__ unsigned short th[64][66];
    __shared__ unsigned short tl[64][66];
    const int tid = threadIdx.x;
    for (int i = tid; i < 64 * 64; i += 256) {
        int ky = i >> 6, hd = i & 63;
        int key = kb + ky;
        unsigned short hv = 0, lv = 0;
        if (key < KLL) {
            size_t o = ((size_t)head * KLL + key) * HDD + hd;
            hv = vr_hi[o]; lv = vr_lo[o];
        }
        th[ky][hd] = hv; tl[ky][hd] = lv;
    }
    __syncthreads();
    for (int i = tid; i < 64 * 64; i += 256) {
        int hd = i >> 6, ky = i & 63;
        size_t o = ((size_t)head * HDD + hd) * VTS + kb + ky;
        vt_hi[o] = th[ky][hd];
        vt_lo[o] = tl[ky][hd];
    }
}

// MFMA GEMM: C[m][n] = A[m][:] . W[n][:] + bias, bf16 hi/lo split (3 cross terms).
// MODE 0: A = xs, out q hi/lo (scaled 0.125). MODE 1: A = mem_rc (ms|xs),
// out k hi/lo (n<512) or vr hi/lo. MODE 2: A = ao, out f32 (+tanh tail rows).
template<int MODE>
__global__ __launch_bounds__(256)
void mfma_proj(const unsigned short* __restrict__ a_hi,
               const unsigned short* __restrict__ a_lo,
               const unsigned short* __restrict__ ms_hi,
               const unsigned short* __restrict__ ms_lo,
               const unsigned short* __restrict__ w_hi,
               const unsigned short* __restrict__ w_lo,
               const float* __restrict__ bias,
               float* __restrict__ out_f,
               unsigned short* __restrict__ oa_hi, unsigned short* __restrict__ oa_lo,
               unsigned short* __restrict__ ob_hi, unsigned short* __restrict__ ob_lo)
{
    const int tid = threadIdx.x;
    const int wv = tid >> 6;
    const int quad = (tid >> 4) & 3;
    const int colk = tid & 15;
    const int m0 = blockIdx.x * 64;
    const int n0 = blockIdx.y * 64;

    // per-lane A row (fragment source), clamped
    const int am = min(m0 + wv * 16 + colk, NROWS - 1);
    const unsigned short *arh, *arl;
    if (MODE == 1) {
        if (am < 48) { arh = ms_hi + (size_t)am * DD; arl = ms_lo + (size_t)am * DD; }
        else         { arh = a_hi + (size_t)(am - 48) * DD; arl = a_lo + (size_t)(am - 48) * DD; }
    } else {
        arh = a_hi + (size_t)am * DD; arl = a_lo + (size_t)am * DD;
    }

    f32x4 acc[4] = {{0,0,0,0},{0,0,0,0},{0,0,0,0},{0,0,0,0}};

    #pragma unroll 2
    for (int k0 = 0; k0 < DD; k0 += 32) {
        short8 ah = *(const short8*)(arh + k0 + quad * 8);
        short8 al = *(const short8*)(arl + k0 + quad * 8);
        #pragma unroll
        for (int nt = 0; nt < 4; ++nt) {
            const size_t wb = (size_t)(n0 + nt * 16 + colk) * DD + k0 + quad * 8;
            short8 bh = *(const short8*)(w_hi + wb);
            short8 bl = *(const short8*)(w_lo + wb);
            acc[nt] = __builtin_amdgcn_mfma_f32_16x16x32_bf16(ah, bh, acc[nt], 0, 0, 0);
            acc[nt] = __builtin_amdgcn_mfma_f32_16x16x32_bf16(ah, bl, acc[nt], 0, 0, 0);
            acc[nt] = __builtin_amdgcn_mfma_f32_16x16x32_bf16(al, bh, acc[nt], 0, 0, 0);
        }
    }

    #pragma unroll
    for (int nt = 0; nt < 4; ++nt) {
        const int nn = n0 + nt * 16 + colk;
        const float bv = bias[nn];
        #pragma unroll
        for (int reg = 0; reg < 4; ++reg) {
            const int m = m0 + wv * 16 + quad * 4 + reg;
            if (m >= NROWS) continue;
            float v = acc[nt][reg] + bv;
            if (MODE == 0) {
                v *= 0.125f;
                int row = m >> 3, bb = m & 7, hh = nn >> 6, hd = nn & 63;
                size_t o = ((size_t)(bb * HH + hh) * TQ + row) * HDD + hd;
                unsigned short hi = f2bf(v);
                oa_hi[o] = hi; oa_lo[o] = f2bf(v - bf2f(hi));
            } else if (MODE == 1) {
                int row = m >> 3, bb = m & 7;
                if (nn < DD) {
                    int hh = nn >> 6, hd = nn & 63;
                    size_t o = ((size_t)(bb * HH + hh) * KLL + row) * HDD + hd;
                    unsigned short hi = f2bf(v);
                    oa_hi[o] = hi; oa_lo[o] = f2bf(v - bf2f(hi));
                } else {
                    int n2 = nn - DD;
                    int hh = n2 >> 6, hd = n2 & 63;
                    size_t o = ((size_t)(bb * HH + hh) * KLL + row) * HDD + hd;
                    unsigned short hi = f2bf(v);
                    ob_hi[o] = hi; ob_lo[o] = f2bf(v - bf2f(hi));
                }
            } else {
                int row = m >> 3;
                if (row >= TQ - MMEM) v = tanhf(v);
                out_f[(size_t)m * DD + nn] = v;
            }
        }
    }
}

union ULds {
    unsigned char pk[TB][800];                                   // 12800 B (pass A)
    struct { unsigned short hi[2][TB][72]; unsigned short lo[2][TB][72]; } p;  // 9216 B (pass B)
};

// Attention v7: all-MFMA (qrk, QK^T, PV), direct-global Q/K/V^T fragments,
// register score cache, two-sweep stats, bf16 hi/lo output for out_proj.
__global__ __launch_bounds__(256, 4)
void attn_kernel(const unsigned short* __restrict__ qh_g,
                 const unsigned short* __restrict__ ql_g,
                 const unsigned short* __restrict__ kh_g,
                 const unsigned short* __restrict__ kl_g,
                 const unsigned short* __restrict__ vt_hi,
                 const unsigned short* __restrict__ vt_lo,
                 const int* __restrict__ lengths,
                 const unsigned char* __restrict__ pk,
                 const unsigned short* __restrict__ rk_hi,
                 const unsigned short* __restrict__ rk_lo,
                 const float* __restrict__ rpe_v,
                 unsigned short* __restrict__ ao_hi,
                 unsigned short* __restrict__ ao_lo)
{
    const int t0 = blockIdx.x * TB;
    const int rows = min(TB, TQ - t0);
    const int n = blockIdx.y;
    const int b = n >> 3;
    const int h = n & 7;
    const int tid = threadIdx.x;
    const int wv = tid >> 6;
    const int quad = (tid >> 4) & 3;
    const int colk = tid & 15;
    const int myk = wv * 16 + colk;

    __shared__ float qrk_l[TB][132];        // qrk, then pr buckets
    __shared__ ULds u;
    __shared__ float4 stats_l[4][TB];

    const int klen = lengths[b] + MMEM + RRCB;

    // phase 0: pk tile -> LDS
    for (int i = tid; i < TB * 200; i += 256) {
        int rr = i / 200, dw = i - rr * 200;
        unsigned w = 0xFFFFFFFFu;
        if (rr < rows) w = ((const unsigned*)pk)[(t0 + rr) * 200 + dw];
        ((unsigned*)&u.pk[rr][0])[dw] = w;
    }

    // A fragments (Q), direct global, held all kernel. A row = query row colk.
    const int qrow = t0 + min(colk, rows - 1);
    const size_t qo = ((size_t)n * TQ + qrow) * HDD;
    short8 ah0 = *(const short8*)(qh_g + qo + quad * 8);
    short8 ah1 = *(const short8*)(qh_g + qo + 32 + quad * 8);
    short8 al0 = *(const short8*)(ql_g + qo + quad * 8);
    short8 al1 = *(const short8*)(ql_g + qo + 32 + quad * 8);

    // qrk via MFMA: wave wv does rpe_k row-tiles wv, wv+4, wv+8
    for (int t = wv; t < 9; t += 4) {
        const size_t rb = (size_t)(t * 16 + colk) * 64;
        short8 bh0 = *(const short8*)(rk_hi + rb + quad * 8);
        short8 bh1 = *(const short8*)(rk_hi + rb + 32 + quad * 8);
        short8 bl0 = *(const short8*)(rk_lo + rb + quad * 8);
        short8 bl1 = *(const short8*)(rk_lo + rb + 32 + quad * 8);
        f32x4 c4 = {0.f, 0.f, 0.f, 0.f};
        c4 = __builtin_amdgcn_mfma_f32_16x16x32_bf16(ah0, bh0, c4, 0, 0, 0);
        c4 = __builtin_amdgcn_mfma_f32_16x16x32_bf16(ah1, bh1, c4, 0, 0, 0);
        c4 = __builtin_amdgcn_mfma_f32_16x16x32_bf16(ah0, bl0, c4, 0, 0, 0);
        c4 = __builtin_amdgcn_mfma_f32_16x16x32_bf16(ah1, bl1, c4, 0, 0, 0);
        c4 = __builtin_amdgcn_mfma_f32_16x16x32_bf16(al0, bh0, c4, 0, 0, 0);
        c4 = __builtin_amdgcn_mfma_f32_16x16x32_bf16(al1, bh1, c4, 0, 0, 0);
        int c = t * 16 + colk;
        if (c <= 128) {
            #pragma unroll
            for (int reg = 0; reg < 4; ++reg) qrk_l[quad * 4 + reg][c] = c4[reg];
        }
    }
    __syncthreads();

    // ---- pass A: QK^T MFMA, record scores + max ----
    float s_reg[NCH][4];
    unsigned rid_pack[NCH];
    float mx[4] = {-1e30f, -1e30f, -1e30f, -1e30f};

    #pragma unroll
    for (int cc = 0; cc < NCH; ++cc) {
        const int key = cc * CH + myk;
        const int krow = min(key, KLL - 1);
        const size_t ko = ((size_t)n * KLL + krow) * HDD;
        short8 bh0 = *(const short8*)(kh_g + ko + quad * 8);
        short8 bh1 = *(const short8*)(kh_g + ko + 32 + quad * 8);
        short8 bl0 = *(const short8*)(kl_g + ko + quad * 8);
        short8 bl1 = *(const short8*)(kl_g + ko + 32 + quad * 8);
        f32x4 c4 = {0.f, 0.f, 0.f, 0.f};
        c4 = __builtin_amdgcn_mfma_f32_16x16x32_bf16(ah0, bh0, c4, 0, 0, 0);
        c4 = __builtin_amdgcn_mfma_f32_16x16x32_bf16(ah1, bh1, c4, 0, 0, 0);
        c4 = __builtin_amdgcn_mfma_f32_16x16x32_bf16(ah0, bl0, c4, 0, 0, 0);
        c4 = __builtin_amdgcn_mfma_f32_16x16x32_bf16(ah1, bl1, c4, 0, 0, 0);
        c4 = __builtin_amdgcn_mfma_f32_16x16x32_bf16(al0, bh0, c4, 0, 0, 0);
        c4 = __builtin_amdgcn_mfma_f32_16x16x32_bf16(al1, bh1, c4, 0, 0, 0);

        const bool vkey = (key < klen);
        unsigned rpack = 0;
        #pragma unroll
        for (int reg = 0; reg < 4; ++reg) {
            const int row = quad * 4 + reg;
            float s = -1e30f;
            unsigned rid = 255u;
            if (vkey && row < rows) {
                rid = u.pk[row][key];
                if (rid != 255u) s = c4[reg] + qrk_l[row][rid];
            }
            rpack |= rid << (8 * reg);
            mx[reg] = fmaxf(mx[reg], s);
            s_reg[cc][reg] = s;
        }
        rid_pack[cc] = rpack;
    }

    // max merge: shfl16 then cross-wave
    #pragma unroll
    for (int reg = 0; reg < 4; ++reg)
        #pragma unroll
        for (int d = 1; d < 16; d <<= 1) mx[reg] = fmaxf(mx[reg], __shfl_xor(mx[reg], d, 16));
    if (colk == 0) {
        #pragma unroll
        for (int reg = 0; reg < 4; ++reg)
            stats_l[wv][quad * 4 + reg] = make_float4(mx[reg], 0.f, 0.f, 0.f);
    }
    __syncthreads();
    if (tid < TB) {
        float M = fmaxf(fmaxf(stats_l[0][tid].x, stats_l[1][tid].x),
                        fmaxf(stats_l[2][tid].x, stats_l[3][tid].x));
        stats_l[0][tid].x = M;
    }
    __syncthreads();

    // e-sweep: e = exp(s - M), overwrite s_reg; accumulate l, l2, count
    float Mr[4], l[4] = {0,0,0,0}, l2[4] = {0,0,0,0}, cn[4] = {0,0,0,0};
    #pragma unroll
    for (int reg = 0; reg < 4; ++reg) Mr[reg] = stats_l[0][quad * 4 + reg].x;
    #pragma unroll
    for (int cc = 0; cc < NCH; ++cc) {
        #pragma unroll
        for (int reg = 0; reg < 4; ++reg) {
            float s = s_reg[cc][reg];
            float e = 0.f;
            if (s > -1e29f) { e = expf(s - Mr[reg]); cn[reg] += 1.f; }
            l[reg] += e;
            l2[reg] = fmaf(e, e, l2[reg]);
            s_reg[cc][reg] = e;
        }
    }
    #pragma unroll
    for (int reg = 0; reg < 4; ++reg)
        #pragma unroll
        for (int d = 1; d < 16; d <<= 1) {
            l[reg]  += __shfl_xor(l[reg], d, 16);
            l2[reg] += __shfl_xor(l2[reg], d, 16);
            cn[reg] += __shfl_xor(cn[reg], d, 16);
        }
    if (colk == 0) {
        #pragma unroll
        for (int reg = 0; reg < 4; ++reg)
            stats_l[wv][quad * 4 + reg] = make_float4(Mr[reg], l[reg], l2[reg], cn[reg]);
    }
    __syncthreads();
    if (tid < TB) {
        float L = 0.f, L2 = 0.f, C = 0.f;
        #pragma unroll
        for (int w = 0; w < 4; ++w) {
            float4 s4 = stats_l[w][tid];
            L += s4.y; L2 += s4.z; C += s4.w;
        }
        float inv = (L > 0.f) ? 1.f / L : 0.f;
        float mean = 1.f / (C + 1e-8f);
        float sump2 = L2 * inv * inv;
        float var = (sump2 - 2.f * mean + C * mean * mean) / (C - 1.f + 1e-8f);
        var = fmaxf(var, 0.f);
        float thr = mean - 0.5f * sqrtf(var);
        stats_l[0][tid] = make_float4(stats_l[0][tid].x, inv, thr, 0.f);
    }
    // zero pr (qrk_l reuse)
    for (int i = tid; i < TB * 132; i += 256) ((float*)qrk_l)[i] = 0.f;
    __syncthreads();

    // ---- pass B: p = e*inv, threshold, buckets, PV via MFMA ----
    float inv_r[4], thr_r[4];
    #pragma unroll
    for (int reg = 0; reg < 4; ++reg) {
        float4 s4 = stats_l[0][quad * 4 + reg];
        inv_r[reg] = s4.y; thr_r[reg] = s4.z;
    }
    float sig[4] = {0.f, 0.f, 0.f, 0.f};
    f32x4 oacc = {0.f, 0.f, 0.f, 0.f};

    auto computeP = [&](int cc, int buf) {
        const unsigned rpack = rid_pack[cc];
        #pragma unroll
        for (int reg = 0; reg < 4; ++reg) {
            const int row = quad * 4 + reg;
            float p = s_reg[cc][reg] * inv_r[reg];
            if (p < thr_r[reg]) p = 0.f;
            if (p > 0.f) {
                sig[reg] += p;
                atomicAdd(&qrk_l[row][(rpack >> (8 * reg)) & 255u], p);
            }
            unsigned short ph = f2bf(p);
            u.p.hi[buf][row][myk] = ph;
            u.p.lo[buf][row][myk] = f2bf(p - bf2f(ph));
        }
    };

    computeP(0, 0);
    __syncthreads();
    for (int cc = 0; cc < NCH; ++cc) {
        const int buf = cc & 1;
        const size_t vbase = ((size_t)n * HDD + wv * 16 + colk) * VTS + cc * CH;
        short8 vh0 = *(const short8*)(vt_hi + vbase + quad * 8);
        short8 vh1 = *(const short8*)(vt_hi + vbase + 32 + quad * 8);
        short8 vl0 = *(const short8*)(vt_lo + vbase + quad * 8);
        short8 vl1 = *(const short8*)(vt_lo + vbase + 32 + quad * 8);
        short8 ph0 = *(const short8*)&u.p.hi[buf][colk][quad * 8];
        short8 ph1 = *(const short8*)&u.p.hi[buf][colk][32 + quad * 8];
        short8 pl0 = *(const short8*)&u.p.lo[buf][colk][quad * 8];
        short8 pl1 = *(const short8*)&u.p.lo[buf][colk][32 + quad * 8];
        oacc = __builtin_amdgcn_mfma_f32_16x16x32_bf16(vh0, ph0, oacc, 0, 0, 0);
        oacc = __builtin_amdgcn_mfma_f32_16x16x32_bf16(vh1, ph1, oacc, 0, 0, 0);
        oacc = __builtin_amdgcn_mfma_f32_16x16x32_bf16(vh0, pl0, oacc, 0, 0, 0);
        oacc = __builtin_amdgcn_mfma_f32_16x16x32_bf16(vh1, pl1, oacc, 0, 0, 0);
        oacc = __builtin_amdgcn_mfma_f32_16x16x32_bf16(vl0, ph0, oacc, 0, 0, 0);
        oacc = __builtin_amdgcn_mfma_f32_16x16x32_bf16(vl1, ph1, oacc, 0, 0, 0);
        if (cc + 1 < NCH) computeP(cc + 1, (cc + 1) & 1);
        __syncthreads();
    }

    // survivor-sum merge
    #pragma unroll
    for (int reg = 0; reg < 4; ++reg)
        #pragma unroll
        for (int d = 1; d < 16; d <<= 1) sig[reg] += __shfl_xor(sig[reg], d, 16);
    if (colk == 0) {
        #pragma unroll
        for (int reg = 0; reg < 4; ++reg)
            stats_l[wv][quad * 4 + reg].w = sig[reg];
    }
    __syncthreads();
    if (tid < TB) {
        float S = stats_l[0][tid].w + stats_l[1][tid].w + stats_l[2][tid].w + stats_l[3][tid].w;
        stats_l[0][tid].w = (S > 0.f) ? 1.f / S : 0.f;
    }
    __syncthreads();

    // output: lane owns O[row=colk][hd = wv*16 + quad*4 .. +3], bf16 hi/lo
    if (colk < rows) {
        float4 ar = {0.f, 0.f, 0.f, 0.f};
        const int hdb = wv * 16 + quad * 4;
        for (int c = 0; c < 129; ++c) {
            float p = qrk_l[colk][c];
            if (p != 0.f) {
                float4 v4 = *(const float4*)(rpe_v + (size_t)c * HDD + hdb);
                ar.x = fmaf(p, v4.x, ar.x);
                ar.y = fmaf(p, v4.y, ar.y);
                ar.z = fmaf(p, v4.z, ar.z);
                ar.w = fmaf(p, v4.w, ar.w);
            }
        }
        const float invS = stats_l[0][colk].w;
        float o0 = (2.f * oacc[0] + ar.x) * invS;
        float o1 = (2.f * oacc[1] + ar.y) * invS;
        float o2 = (2.f * oacc[2] + ar.z) * invS;
        float o3 = (2.f * oacc[3] + ar.w) * invS;
        size_t oo = ((size_t)(t0 + colk) * BB + b) * DD + h * HDD + hdb;
        ushort4 oh, ol;
        oh.x = f2bf(o0); ol.x = f2bf(o0 - bf2f(oh.x));
        oh.y = f2bf(o1); ol.y = f2bf(o1 - bf2f(oh.y));
        oh.z = f2bf(o2); ol.z = f2bf(o2 - bf2f(oh.z));
        oh.w = f2bf(o3); ol.w = f2bf(o3 - bf2f(oh.w));
        *(ushort4*)(ao_hi + oo) = oh;
        *(ushort4*)(ao_lo + oo) = ol;
    }
}

extern "C" void kernel_launch(void* const* d_in, const int* in_sizes, int n_in,
                              void* d_out, int out_size, void* d_ws, size_t ws_size,
                              hipStream_t stream) {
    const float*          x      = (const float*)d_in[0];
    const int*            lengths= (const int*)d_in[1];
    const float*          mems   = (const float*)d_in[2];
    const void*           amask  = (const void*)d_in[3];
    const int*            rpe    = (const int*)d_in[4];
    const float*          wq     = (const float*)d_in[6];
    const float*          bq     = (const float*)d_in[7];
    const float*          wkv    = (const float*)d_in[8];
    const float*          bkv    = (const float*)d_in[9];
    const float*          wo     = (const float*)d_in[10];
    const float*          bo     = (const float*)d_in[11];
    const float*          rpe_k  = (const float*)d_in[12];
    const float*          rpe_v  = (const float*)d_in[13];

    const size_t NE = (size_t)NROWS * DD;           // 3,268,608
    const size_t VTN = (size_t)NHEADS * HDD * VTS;  // 3,407,872

    char* p = (char*)d_ws;
    unsigned short* q_hi = (unsigned short*)p;  p += NE * 2;
    unsigned short* q_lo = (unsigned short*)p;  p += NE * 2;
    // union region: xs/ms (proj inputs, dead after proj1) | vt (written after)
    char* uni = p;                              p += VTN * 4;   // vt is the larger
    unsigned short* xs_hi = (unsigned short*)uni;
    unsigned short* xs_lo = xs_hi + NE;
    unsigned short* ms_hi = xs_lo + NE;
    unsigned short* ms_lo = ms_hi + 48 * DD;
    unsigned short* vt_hi = (unsigned short*)uni;
    unsigned short* vt_lo = vt_hi + VTN;
    unsigned short* w_hi = (unsigned short*)p;  p += (size_t)2048 * DD * 2;
    unsigned short* w_lo = (unsigned short*)p;  p += (size_t)2048 * DD * 2;
    unsigned short* k_hi = (unsigned short*)p;  p += NE * 2;
    unsigned short* k_lo = (unsigned short*)p;  p += NE * 2;
    unsigned short* vr_hi = (unsigned short*)p; p += NE * 2;   // aliased by ao after transpose
    unsigned short* vr_lo = (unsigned short*)p; p += NE * 2;
    unsigned short* ao_hi = vr_hi;
    unsigned short* ao_lo = vr_lo;
    unsigned short* rk_hi = (unsigned short*)p; p += 144 * 64 * 2;
    unsigned short* rk_lo = (unsigned short*)p; p += 144 * 64 * 2;
    unsigned char*  pk    = (unsigned char*)p;  p += (size_t)TT * 800;
    int* mmode = (int*)p;

    detect_mask_kernel<<<1, 1024, 0, stream>>>((const unsigned int*)amask, mmode);
    pack_kernel<<<(TT * 200 + 255) / 256, 256, 0, stream>>>(amask, rpe, mmode, (unsigned int*)pk);
    rpe_prep_kernel<<<36, 256, 0, stream>>>(rpe_k, rk_hi, rk_lo);
    {
        const size_t total = NE + (size_t)48 * DD + (size_t)2048 * DD;
        split_kernel<<<(int)((total + 255) / 256), 256, 0, stream>>>(
            x, mems, wq, wkv, wo, xs_hi, xs_lo, ms_hi, ms_lo, w_hi, w_lo);
    }
    mfma_proj<0><<<dim3(100, 8), 256, 0, stream>>>(
        xs_hi, xs_lo, nullptr, nullptr, w_hi, w_lo, bq,
        nullptr, q_hi, q_lo, nullptr, nullptr);
    mfma_proj<1><<<dim3(100, 16), 256, 0, stream>>>(
        xs_hi, xs_lo, ms_hi, ms_lo, w_hi + (size_t)512 * DD, w_lo + (size_t)512 * DD, bkv,
        nullptr, k_hi, k_lo, vr_hi, vr_lo);
    transpose_v_kernel<<<dim3(13, NHEADS), 256, 0, stream>>>(vr_hi, vr_lo, vt_hi, vt_lo);
    attn_kernel<<<dim3(50, NHEADS), 256, 0, stream>>>(
        q_hi, q_lo, k_hi, k_lo, vt_hi, vt_lo, lengths, pk, rk_hi, rk_lo, rpe_v, ao_hi, ao_lo);
    mfma_proj<2><<<dim3(100, 8), 256, 0, stream>>>(
        ao_hi, ao_lo, nullptr, nullptr, w_hi + (size_t)1536 * DD, w_lo + (size_t)1536 * DD, bo,
        (float*)d_out, nullptr, nullptr, nullptr, nullptr);
}

// Round 12
// 767.547 us; speedup vs baseline: 1.9068x; 1.0090x over previous
//
#include <hip/hip_runtime.h>
#include <hip/hip_bf16.h>
#include <math.h>

// Problem constants (fixed by the reference)
#define TT   799
#define BB   8
#define DD   512
#define HH   8
#define HDD  64
#define MMEM 6
#define RRCB 24
#define KLL  798
#define TQ   798            // query rows actually needed (row 798 unused)
#define NROWS (TQ * BB)     // 6384
#define NHEADS 64           // B*H
#define NEG_INF (-INFINITY)

#define TB   16             // t-rows per attention block
#define CH   64             // keys per MFMA chunk
#define NCH  13             // 13*64 = 832 >= 798
#define VTS  832            // v_t row stride in keys

static_assert(NROWS == 6384, "");

typedef __attribute__((ext_vector_type(8))) short short8;
typedef __attribute__((ext_vector_type(4))) float f32x4;

__device__ __forceinline__ unsigned short f2bf(float x) {
    union { float f; unsigned u; } c; c.f = x;
    unsigned r = c.u + 0x7FFFu + ((c.u >> 16) & 1u);   // RNE
    return (unsigned short)(r >> 16);
}
__device__ __forceinline__ float bf2f(unsigned short b) {
    union { unsigned u; float f; } c; c.u = ((unsigned)b) << 16; return c.f;
}

// mode 0 = int32 (0/1), mode 1 = float32 (0.0/1.0), mode 2 = uint8 bool.
__global__ void detect_mask_kernel(const unsigned int* __restrict__ a,
                                   int* __restrict__ mode)
{
    __shared__ int c0s, cHs;
    if (threadIdx.x == 0) { c0s = 0; cHs = 0; }
    __syncthreads();
    int c0 = 0, cH = 0;
    const int ND = 4096;
    for (int i = threadIdx.x; i < ND; i += blockDim.x) {
        unsigned int w = a[i];
        if (w & 0x000000FFu) c0++;
        if (w & 0xFFFFFF00u) cH++;
    }
    atomicAdd(&c0s, c0); atomicAdd(&cHs, cH);
    __syncthreads();
    if (threadIdx.x == 0)
        *mode = (cHs == 0) ? 0 : ((c0s == 0) ? 1 : 2);
}

// Fused prep: pack (mask,rpe)->rid bytes | rpe_k hi/lo split | x/mems/W hi/lo split.
#define PK_BLOCKS 625
#define RK_BLOCKS 36
__global__ __launch_bounds__(256)
void prep_kernel(const void* __restrict__ amask,
                 const int* __restrict__ rpe,
                 const int* __restrict__ mode_p,
                 unsigned int* __restrict__ pk,
                 const float* __restrict__ rpe_k,
                 unsigned short* __restrict__ rk_hi,
                 unsigned short* __restrict__ rk_lo,
                 const float* __restrict__ x,
                 const float* __restrict__ mems,
                 const float* __restrict__ wq,
                 const float* __restrict__ wkv,
                 const float* __restrict__ wo,
                 unsigned short* __restrict__ xs_hi, unsigned short* __restrict__ xs_lo,
                 unsigned short* __restrict__ ms_hi, unsigned short* __restrict__ ms_lo,
                 unsigned short* __restrict__ w_hi,  unsigned short* __restrict__ w_lo)
{
    const int bid = blockIdx.x;
    const int tid = threadIdx.x;
    if (bid < PK_BLOCKS) {
        const int mode = *mode_p;
        int i = bid * 256 + tid;
        if (i >= TT * 200) return;
        int t = i / 200;
        int kbase = (i - t * 200) * 4;
        unsigned out = 0;
        #pragma unroll
        for (int u = 0; u < 4; ++u) {
            int k = kbase + u;
            unsigned byte = 255u;
            if (k < KLL) {
                size_t idx = (size_t)t * KLL + k;
                bool masked;
                if (mode == 0)      masked = (((const int*)amask)[idx] != 0);
                else if (mode == 1) masked = (((const float*)amask)[idx] != 0.f);
                else                masked = (((const unsigned char*)amask)[idx] != 0);
                byte = masked ? 255u : (unsigned)rpe[idx];
            }
            out |= byte << (8 * u);
        }
        pk[i] = out;
    } else if (bid < PK_BLOCKS + RK_BLOCKS) {
        int i = (bid - PK_BLOCKS) * 256 + tid;
        if (i >= 144 * 64) return;
        int c = i >> 6;
        float v = (c < 129) ? rpe_k[i] : 0.f;
        unsigned short hi = f2bf(v);
        rk_hi[i] = hi;
        rk_lo[i] = f2bf(v - bf2f(hi));
    } else {
        const size_t NX = (size_t)NROWS * DD;
        const size_t NM = 48 * DD;
        const size_t NW = 2048 * DD;
        size_t i = (size_t)(bid - PK_BLOCKS - RK_BLOCKS) * 256 + tid;
        float v; unsigned short *dh, *dl; size_t o;
        if (i < NX) { o = i; v = x[o]; dh = xs_hi; dl = xs_lo; }
        else if (i < NX + NM) { o = i - NX; v = mems[o]; dh = ms_hi; dl = ms_lo; }
        else if (i < NX + NM + NW) {
            o = i - NX - NM;
            size_t r = o >> 9;
            if (r < 512) v = wq[o];
            else if (r < 1536) v = wkv[o - (size_t)512 * DD];
            else v = wo[o - (size_t)1536 * DD];
            dh = w_hi; dl = w_lo;
        } else return;
        unsigned short hi = f2bf(v);
        dh[o] = hi;
        dl[o] = f2bf(v - bf2f(hi));
    }
}

// v row-major bf16 hi/lo [head][key][hd] -> v_t [head][hd][VTS] (keys 798..831 zero)
__global__ __launch_bounds__(256)
void transpose_v_kernel(const unsigned short* __restrict__ vr_hi,
                        const unsigned short* __restrict__ vr_lo,
                        unsigned short* __restrict__ vt_hi,
                        unsigned short* __restrict__ vt_lo)
{
    const int head = blockIdx.y;
    const int kb = blockIdx.x * 64;
    __shared__ unsigned short th[64][66];
    __shared__ unsigned short tl[64][66];
    const int tid = threadIdx.x;
    for (int i = tid; i < 64 * 64; i += 256) {
        int ky = i >> 6, hd = i & 63;
        int key = kb + ky;
        unsigned short hv = 0, lv = 0;
        if (key < KLL) {
            size_t o = ((size_t)head * KLL + key) * HDD + hd;
            hv = vr_hi[o]; lv = vr_lo[o];
        }
        th[ky][hd] = hv; tl[ky][hd] = lv;
    }
    __syncthreads();
    for (int i = tid; i < 64 * 64; i += 256) {
        int hd = i >> 6, ky = i & 63;
        size_t o = ((size_t)head * HDD + hd) * VTS + kb + ky;
        vt_hi[o] = th[ky][hd];
        vt_lo[o] = tl[ky][hd];
    }
}

// MFMA GEMM: C[m][n] = A[m][:] . W[n][:] + bias, bf16 hi/lo split (3 cross terms).
// MODE 0: A = xs, out q hi/lo (scaled 0.125). MODE 1: A = mem_rc (ms|xs),
// out k hi/lo (n<512) or vr hi/lo. MODE 2: A = ao, out f32 (+tanh tail rows).
template<int MODE>
__global__ __launch_bounds__(256)
void mfma_proj(const unsigned short* __restrict__ a_hi,
               const unsigned short* __restrict__ a_lo,
               const unsigned short* __restrict__ ms_hi,
               const unsigned short* __restrict__ ms_lo,
               const unsigned short* __restrict__ w_hi,
               const unsigned short* __restrict__ w_lo,
               const float* __restrict__ bias,
               float* __restrict__ out_f,
               unsigned short* __restrict__ oa_hi, unsigned short* __restrict__ oa_lo,
               unsigned short* __restrict__ ob_hi, unsigned short* __restrict__ ob_lo)
{
    const int tid = threadIdx.x;
    const int wv = tid >> 6;
    const int quad = (tid >> 4) & 3;
    const int colk = tid & 15;
    const int m0 = blockIdx.x * 64;
    const int n0 = blockIdx.y * 64;

    const int am = min(m0 + wv * 16 + colk, NROWS - 1);
    const unsigned short *arh, *arl;
    if (MODE == 1) {
        if (am < 48) { arh = ms_hi + (size_t)am * DD; arl = ms_lo + (size_t)am * DD; }
        else         { arh = a_hi + (size_t)(am - 48) * DD; arl = a_lo + (size_t)(am - 48) * DD; }
    } else {
        arh = a_hi + (size_t)am * DD; arl = a_lo + (size_t)am * DD;
    }

    f32x4 acc[4] = {{0,0,0,0},{0,0,0,0},{0,0,0,0},{0,0,0,0}};

    #pragma unroll 2
    for (int k0 = 0; k0 < DD; k0 += 32) {
        short8 ah = *(const short8*)(arh + k0 + quad * 8);
        short8 al = *(const short8*)(arl + k0 + quad * 8);
        #pragma unroll
        for (int nt = 0; nt < 4; ++nt) {
            const size_t wb = (size_t)(n0 + nt * 16 + colk) * DD + k0 + quad * 8;
            short8 bh = *(const short8*)(w_hi + wb);
            short8 bl = *(const short8*)(w_lo + wb);
            acc[nt] = __builtin_amdgcn_mfma_f32_16x16x32_bf16(ah, bh, acc[nt], 0, 0, 0);
            acc[nt] = __builtin_amdgcn_mfma_f32_16x16x32_bf16(ah, bl, acc[nt], 0, 0, 0);
            acc[nt] = __builtin_amdgcn_mfma_f32_16x16x32_bf16(al, bh, acc[nt], 0, 0, 0);
        }
    }

    #pragma unroll
    for (int nt = 0; nt < 4; ++nt) {
        const int nn = n0 + nt * 16 + colk;
        const float bv = bias[nn];
        #pragma unroll
        for (int reg = 0; reg < 4; ++reg) {
            const int m = m0 + wv * 16 + quad * 4 + reg;
            if (m >= NROWS) continue;
            float v = acc[nt][reg] + bv;
            if (MODE == 0) {
                v *= 0.125f;
                int row = m >> 3, bb = m & 7, hh = nn >> 6, hd = nn & 63;
                size_t o = ((size_t)(bb * HH + hh) * TQ + row) * HDD + hd;
                unsigned short hi = f2bf(v);
                oa_hi[o] = hi; oa_lo[o] = f2bf(v - bf2f(hi));
            } else if (MODE == 1) {
                int row = m >> 3, bb = m & 7;
                if (nn < DD) {
                    int hh = nn >> 6, hd = nn & 63;
                    size_t o = ((size_t)(bb * HH + hh) * KLL + row) * HDD + hd;
                    unsigned short hi = f2bf(v);
                    oa_hi[o] = hi; oa_lo[o] = f2bf(v - bf2f(hi));
                } else {
                    int n2 = nn - DD;
                    int hh = n2 >> 6, hd = n2 & 63;
                    size_t o = ((size_t)(bb * HH + hh) * KLL + row) * HDD + hd;
                    unsigned short hi = f2bf(v);
                    ob_hi[o] = hi; ob_lo[o] = f2bf(v - bf2f(hi));
                }
            } else {
                int row = m >> 3;
                if (row >= TQ - MMEM) v = tanhf(v);
                out_f[(size_t)m * DD + nn] = v;
            }
        }
    }
}

union ULds {
    unsigned char pk[TB][800];                                   // 12800 B (pass A)
    struct { unsigned short hi[2][TB][72]; unsigned short lo[2][TB][72]; } p;  // 9216 B (pass B)
};

// Attention v8: all-MFMA, XCD-swizzled 1D grid — all 50 t-blocks of a head
// land on the same XCD (id&7) so K/V^T stay L2-resident per XCD.
__global__ __launch_bounds__(256, 4)
void attn_kernel(const unsigned short* __restrict__ qh_g,
                 const unsigned short* __restrict__ ql_g,
                 const unsigned short* __restrict__ kh_g,
                 const unsigned short* __restrict__ kl_g,
                 const unsigned short* __restrict__ vt_hi,
                 const unsigned short* __restrict__ vt_lo,
                 const int* __restrict__ lengths,
                 const unsigned char* __restrict__ pk,
                 const unsigned short* __restrict__ rk_hi,
                 const unsigned short* __restrict__ rk_lo,
                 const float* __restrict__ rpe_v,
                 unsigned short* __restrict__ ao_hi,
                 unsigned short* __restrict__ ao_lo)
{
    // XCD-aware decode: xcd = id&7 fixed per head; t-chunks consecutive.
    const int id = blockIdx.x;
    const int xcd = id & 7;
    const int grp = id >> 3;             // 0..399
    const int t_chunk = grp % 50;
    const int n = (grp / 50) * 8 + xcd;  // head index 0..63
    const int t0 = t_chunk * TB;
    const int rows = min(TB, TQ - t0);
    const int b = n >> 3;
    const int h = n & 7;
    const int tid = threadIdx.x;
    const int wv = tid >> 6;
    const int quad = (tid >> 4) & 3;
    const int colk = tid & 15;
    const int myk = wv * 16 + colk;

    __shared__ float qrk_l[TB][132];        // qrk, then pr buckets
    __shared__ ULds u;
    __shared__ float4 stats_l[4][TB];

    const int klen = lengths[b] + MMEM + RRCB;

    // phase 0: pk tile -> LDS
    for (int i = tid; i < TB * 200; i += 256) {
        int rr = i / 200, dw = i - rr * 200;
        unsigned w = 0xFFFFFFFFu;
        if (rr < rows) w = ((const unsigned*)pk)[(t0 + rr) * 200 + dw];
        ((unsigned*)&u.pk[rr][0])[dw] = w;
    }

    // A fragments (Q), direct global, held all kernel. A row = query row colk.
    const int qrow = t0 + min(colk, rows - 1);
    const size_t qo = ((size_t)n * TQ + qrow) * HDD;
    short8 ah0 = *(const short8*)(qh_g + qo + quad * 8);
    short8 ah1 = *(const short8*)(qh_g + qo + 32 + quad * 8);
    short8 al0 = *(const short8*)(ql_g + qo + quad * 8);
    short8 al1 = *(const short8*)(ql_g + qo + 32 + quad * 8);

    // qrk via MFMA: wave wv does rpe_k row-tiles wv, wv+4, wv+8
    for (int t = wv; t < 9; t += 4) {
        const size_t rb = (size_t)(t * 16 + colk) * 64;
        short8 bh0 = *(const short8*)(rk_hi + rb + quad * 8);
        short8 bh1 = *(const short8*)(rk_hi + rb + 32 + quad * 8);
        short8 bl0 = *(const short8*)(rk_lo + rb + quad * 8);
        short8 bl1 = *(const short8*)(rk_lo + rb + 32 + quad * 8);
        f32x4 c4 = {0.f, 0.f, 0.f, 0.f};
        c4 = __builtin_amdgcn_mfma_f32_16x16x32_bf16(ah0, bh0, c4, 0, 0, 0);
        c4 = __builtin_amdgcn_mfma_f32_16x16x32_bf16(ah1, bh1, c4, 0, 0, 0);
        c4 = __builtin_amdgcn_mfma_f32_16x16x32_bf16(ah0, bl0, c4, 0, 0, 0);
        c4 = __builtin_amdgcn_mfma_f32_16x16x32_bf16(ah1, bl1, c4, 0, 0, 0);
        c4 = __builtin_amdgcn_mfma_f32_16x16x32_bf16(al0, bh0, c4, 0, 0, 0);
        c4 = __builtin_amdgcn_mfma_f32_16x16x32_bf16(al1, bh1, c4, 0, 0, 0);
        int c = t * 16 + colk;
        if (c <= 128) {
            #pragma unroll
            for (int reg = 0; reg < 4; ++reg) qrk_l[quad * 4 + reg][c] = c4[reg];
        }
    }
    __syncthreads();

    // ---- pass A: QK^T MFMA, record scores + max ----
    float s_reg[NCH][4];
    unsigned rid_pack[NCH];
    float mx[4] = {-1e30f, -1e30f, -1e30f, -1e30f};

    #pragma unroll
    for (int cc = 0; cc < NCH; ++cc) {
        const int key = cc * CH + myk;
        const int krow = min(key, KLL - 1);
        const size_t ko = ((size_t)n * KLL + krow) * HDD;
        short8 bh0 = *(const short8*)(kh_g + ko + quad * 8);
        short8 bh1 = *(const short8*)(kh_g + ko + 32 + quad * 8);
        short8 bl0 = *(const short8*)(kl_g + ko + quad * 8);
        short8 bl1 = *(const short8*)(kl_g + ko + 32 + quad * 8);
        f32x4 c4 = {0.f, 0.f, 0.f, 0.f};
        c4 = __builtin_amdgcn_mfma_f32_16x16x32_bf16(ah0, bh0, c4, 0, 0, 0);
        c4 = __builtin_amdgcn_mfma_f32_16x16x32_bf16(ah1, bh1, c4, 0, 0, 0);
        c4 = __builtin_amdgcn_mfma_f32_16x16x32_bf16(ah0, bl0, c4, 0, 0, 0);
        c4 = __builtin_amdgcn_mfma_f32_16x16x32_bf16(ah1, bl1, c4, 0, 0, 0);
        c4 = __builtin_amdgcn_mfma_f32_16x16x32_bf16(al0, bh0, c4, 0, 0, 0);
        c4 = __builtin_amdgcn_mfma_f32_16x16x32_bf16(al1, bh1, c4, 0, 0, 0);

        const bool vkey = (key < klen);
        unsigned rpack = 0;
        #pragma unroll
        for (int reg = 0; reg < 4; ++reg) {
            const int row = quad * 4 + reg;
            float s = -1e30f;
            unsigned rid = 255u;
            if (vkey && row < rows) {
                rid = u.pk[row][key];
                if (rid != 255u) s = c4[reg] + qrk_l[row][rid];
            }
            rpack |= rid << (8 * reg);
            mx[reg] = fmaxf(mx[reg], s);
            s_reg[cc][reg] = s;
        }
        rid_pack[cc] = rpack;
    }

    // max merge: shfl16 then cross-wave
    #pragma unroll
    for (int reg = 0; reg < 4; ++reg)
        #pragma unroll
        for (int d = 1; d < 16; d <<= 1) mx[reg] = fmaxf(mx[reg], __shfl_xor(mx[reg], d, 16));
    if (colk == 0) {
        #pragma unroll
        for (int reg = 0; reg < 4; ++reg)
            stats_l[wv][quad * 4 + reg] = make_float4(mx[reg], 0.f, 0.f, 0.f);
    }
    __syncthreads();
    if (tid < TB) {
        float M = fmaxf(fmaxf(stats_l[0][tid].x, stats_l[1][tid].x),
                        fmaxf(stats_l[2][tid].x, stats_l[3][tid].x));
        stats_l[0][tid].x = M;
    }
    __syncthreads();

    // e-sweep: e = exp(s - M), overwrite s_reg; accumulate l, l2, count
    float Mr[4], l[4] = {0,0,0,0}, l2[4] = {0,0,0,0}, cn[4] = {0,0,0,0};
    #pragma unroll
    for (int reg = 0; reg < 4; ++reg) Mr[reg] = stats_l[0][quad * 4 + reg].x;
    #pragma unroll
    for (int cc = 0; cc < NCH; ++cc) {
        #pragma unroll
        for (int reg = 0; reg < 4; ++reg) {
            float s = s_reg[cc][reg];
            float e = 0.f;
            if (s > -1e29f) { e = expf(s - Mr[reg]); cn[reg] += 1.f; }
            l[reg] += e;
            l2[reg] = fmaf(e, e, l2[reg]);
            s_reg[cc][reg] = e;
        }
    }
    #pragma unroll
    for (int reg = 0; reg < 4; ++reg)
        #pragma unroll
        for (int d = 1; d < 16; d <<= 1) {
            l[reg]  += __shfl_xor(l[reg], d, 16);
            l2[reg] += __shfl_xor(l2[reg], d, 16);
            cn[reg] += __shfl_xor(cn[reg], d, 16);
        }
    if (colk == 0) {
        #pragma unroll
        for (int reg = 0; reg < 4; ++reg)
            stats_l[wv][quad * 4 + reg] = make_float4(Mr[reg], l[reg], l2[reg], cn[reg]);
    }
    __syncthreads();
    if (tid < TB) {
        float L = 0.f, L2 = 0.f, C = 0.f;
        #pragma unroll
        for (int w = 0; w < 4; ++w) {
            float4 s4 = stats_l[w][tid];
            L += s4.y; L2 += s4.z; C += s4.w;
        }
        float inv = (L > 0.f) ? 1.f / L : 0.f;
        float mean = 1.f / (C + 1e-8f);
        float sump2 = L2 * inv * inv;
        float var = (sump2 - 2.f * mean + C * mean * mean) / (C - 1.f + 1e-8f);
        var = fmaxf(var, 0.f);
        float thr = mean - 0.5f * sqrtf(var);
        stats_l[0][tid] = make_float4(stats_l[0][tid].x, inv, thr, 0.f);
    }
    // zero pr (qrk_l reuse)
    for (int i = tid; i < TB * 132; i += 256) ((float*)qrk_l)[i] = 0.f;
    __syncthreads();

    // ---- pass B: p = e*inv, threshold, buckets, PV via MFMA ----
    float inv_r[4], thr_r[4];
    #pragma unroll
    for (int reg = 0; reg < 4; ++reg) {
        float4 s4 = stats_l[0][quad * 4 + reg];
        inv_r[reg] = s4.y; thr_r[reg] = s4.z;
    }
    float sig[4] = {0.f, 0.f, 0.f, 0.f};
    f32x4 oacc = {0.f, 0.f, 0.f, 0.f};

    auto computeP = [&](int cc, int buf) {
        const unsigned rpack = rid_pack[cc];
        #pragma unroll
        for (int reg = 0; reg < 4; ++reg) {
            const int row = quad * 4 + reg;
            float p = s_reg[cc][reg] * inv_r[reg];
            if (p < thr_r[reg]) p = 0.f;
            if (p > 0.f) {
                sig[reg] += p;
                atomicAdd(&qrk_l[row][(rpack >> (8 * reg)) & 255u], p);
            }
            unsigned short ph = f2bf(p);
            u.p.hi[buf][row][myk] = ph;
            u.p.lo[buf][row][myk] = f2bf(p - bf2f(ph));
        }
    };

    computeP(0, 0);
    __syncthreads();
    for (int cc = 0; cc < NCH; ++cc) {
        const int buf = cc & 1;
        const size_t vbase = ((size_t)n * HDD + wv * 16 + colk) * VTS + cc * CH;
        short8 vh0 = *(const short8*)(vt_hi + vbase + quad * 8);
        short8 vh1 = *(const short8*)(vt_hi + vbase + 32 + quad * 8);
        short8 vl0 = *(const short8*)(vt_lo + vbase + quad * 8);
        short8 vl1 = *(const short8*)(vt_lo + vbase + 32 + quad * 8);
        short8 ph0 = *(const short8*)&u.p.hi[buf][colk][quad * 8];
        short8 ph1 = *(const short8*)&u.p.hi[buf][colk][32 + quad * 8];
        short8 pl0 = *(const short8*)&u.p.lo[buf][colk][quad * 8];
        short8 pl1 = *(const short8*)&u.p.lo[buf][colk][32 + quad * 8];
        oacc = __builtin_amdgcn_mfma_f32_16x16x32_bf16(vh0, ph0, oacc, 0, 0, 0);
        oacc = __builtin_amdgcn_mfma_f32_16x16x32_bf16(vh1, ph1, oacc, 0, 0, 0);
        oacc = __builtin_amdgcn_mfma_f32_16x16x32_bf16(vh0, pl0, oacc, 0, 0, 0);
        oacc = __builtin_amdgcn_mfma_f32_16x16x32_bf16(vh1, pl1, oacc, 0, 0, 0);
        oacc = __builtin_amdgcn_mfma_f32_16x16x32_bf16(vl0, ph0, oacc, 0, 0, 0);
        oacc = __builtin_amdgcn_mfma_f32_16x16x32_bf16(vl1, ph1, oacc, 0, 0, 0);
        if (cc + 1 < NCH) computeP(cc + 1, (cc + 1) & 1);
        __syncthreads();
    }

    // survivor-sum merge
    #pragma unroll
    for (int reg = 0; reg < 4; ++reg)
        #pragma unroll
        for (int d = 1; d < 16; d <<= 1) sig[reg] += __shfl_xor(sig[reg], d, 16);
    if (colk == 0) {
        #pragma unroll
        for (int reg = 0; reg < 4; ++reg)
            stats_l[wv][quad * 4 + reg].w = sig[reg];
    }
    __syncthreads();
    if (tid < TB) {
        float S = stats_l[0][tid].w + stats_l[1][tid].w + stats_l[2][tid].w + stats_l[3][tid].w;
        stats_l[0][tid].w = (S > 0.f) ? 1.f / S : 0.f;
    }
    __syncthreads();

    // output: lane owns O[row=colk][hd = wv*16 + quad*4 .. +3], bf16 hi/lo
    if (colk < rows) {
        float4 ar = {0.f, 0.f, 0.f, 0.f};
        const int hdb = wv * 16 + quad * 4;
        for (int c = 0; c < 129; ++c) {
            float p = qrk_l[colk][c];
            if (p != 0.f) {
                float4 v4 = *(const float4*)(rpe_v + (size_t)c * HDD + hdb);
                ar.x = fmaf(p, v4.x, ar.x);
                ar.y = fmaf(p, v4.y, ar.y);
                ar.z = fmaf(p, v4.z, ar.z);
                ar.w = fmaf(p, v4.w, ar.w);
            }
        }
        const float invS = stats_l[0][colk].w;
        float o0 = (2.f * oacc[0] + ar.x) * invS;
        float o1 = (2.f * oacc[1] + ar.y) * invS;
        float o2 = (2.f * oacc[2] + ar.z) * invS;
        float o3 = (2.f * oacc[3] + ar.w) * invS;
        size_t oo = ((size_t)(t0 + colk) * BB + b) * DD + h * HDD + hdb;
        ushort4 oh, ol;
        oh.x = f2bf(o0); ol.x = f2bf(o0 - bf2f(oh.x));
        oh.y = f2bf(o1); ol.y = f2bf(o1 - bf2f(oh.y));
        oh.z = f2bf(o2); ol.z = f2bf(o2 - bf2f(oh.z));
        oh.w = f2bf(o3); ol.w = f2bf(o3 - bf2f(oh.w));
        *(ushort4*)(ao_hi + oo) = oh;
        *(ushort4*)(ao_lo + oo) = ol;
    }
}

extern "C" void kernel_launch(void* const* d_in, const int* in_sizes, int n_in,
                              void* d_out, int out_size, void* d_ws, size_t ws_size,
                              hipStream_t stream) {
    const float*          x      = (const float*)d_in[0];
    const int*            lengths= (const int*)d_in[1];
    const float*          mems   = (const float*)d_in[2];
    const void*           amask  = (const void*)d_in[3];
    const int*            rpe    = (const int*)d_in[4];
    const float*          wq     = (const float*)d_in[6];
    const float*          bq     = (const float*)d_in[7];
    const float*          wkv    = (const float*)d_in[8];
    const float*          bkv    = (const float*)d_in[9];
    const float*          wo     = (const float*)d_in[10];
    const float*          bo     = (const float*)d_in[11];
    const float*          rpe_k  = (const float*)d_in[12];
    const float*          rpe_v  = (const float*)d_in[13];

    const size_t NE = (size_t)NROWS * DD;           // 3,268,608
    const size_t VTN = (size_t)NHEADS * HDD * VTS;  // 3,407,872

    char* p = (char*)d_ws;
    unsigned short* q_hi = (unsigned short*)p;  p += NE * 2;
    unsigned short* q_lo = (unsigned short*)p;  p += NE * 2;
    // union region: xs/ms (proj inputs, dead after proj1) | vt (written after)
    char* uni = p;                              p += VTN * 4;   // vt is the larger
    unsigned short* xs_hi = (unsigned short*)uni;
    unsigned short* xs_lo = xs_hi + NE;
    unsigned short* ms_hi = xs_lo + NE;
    unsigned short* ms_lo = ms_hi + 48 * DD;
    unsigned short* vt_hi = (unsigned short*)uni;
    unsigned short* vt_lo = vt_hi + VTN;
    unsigned short* w_hi = (unsigned short*)p;  p += (size_t)2048 * DD * 2;
    unsigned short* w_lo = (unsigned short*)p;  p += (size_t)2048 * DD * 2;
    unsigned short* k_hi = (unsigned short*)p;  p += NE * 2;
    unsigned short* k_lo = (unsigned short*)p;  p += NE * 2;
    unsigned short* vr_hi = (unsigned short*)p; p += NE * 2;   // aliased by ao after transpose
    unsigned short* vr_lo = (unsigned short*)p; p += NE * 2;
    unsigned short* ao_hi = vr_hi;
    unsigned short* ao_lo = vr_lo;
    unsigned short* rk_hi = (unsigned short*)p; p += 144 * 64 * 2;
    unsigned short* rk_lo = (unsigned short*)p; p += 144 * 64 * 2;
    unsigned char*  pk    = (unsigned char*)p;  p += (size_t)TT * 800;
    int* mmode = (int*)p;

    detect_mask_kernel<<<1, 1024, 0, stream>>>((const unsigned int*)amask, mmode);
    {
        const size_t sp_total = NE + (size_t)48 * DD + (size_t)2048 * DD;  // 4,341,760
        const int sp_blocks = (int)((sp_total + 255) / 256);               // 16,960
        prep_kernel<<<PK_BLOCKS + RK_BLOCKS + sp_blocks, 256, 0, stream>>>(
            amask, rpe, mmode, (unsigned int*)pk,
            rpe_k, rk_hi, rk_lo,
            x, mems, wq, wkv, wo,
            xs_hi, xs_lo, ms_hi, ms_lo, w_hi, w_lo);
    }
    mfma_proj<0><<<dim3(100, 8), 256, 0, stream>>>(
        xs_hi, xs_lo, nullptr, nullptr, w_hi, w_lo, bq,
        nullptr, q_hi, q_lo, nullptr, nullptr);
    mfma_proj<1><<<dim3(100, 16), 256, 0, stream>>>(
        xs_hi, xs_lo, ms_hi, ms_lo, w_hi + (size_t)512 * DD, w_lo + (size_t)512 * DD, bkv,
        nullptr, k_hi, k_lo, vr_hi, vr_lo);
    transpose_v_kernel<<<dim3(13, NHEADS), 256, 0, stream>>>(vr_hi, vr_lo, vt_hi, vt_lo);
    attn_kernel<<<3200, 256, 0, stream>>>(
        q_hi, q_lo, k_hi, k_lo, vt_hi, vt_lo, lengths, pk, rk_hi, rk_lo, rpe_v, ao_hi, ao_lo);
    mfma_proj<2><<<dim3(100, 8), 256, 0, stream>>>(
        ao_hi, ao_lo, nullptr, nullptr, w_hi + (size_t)1536 * DD, w_lo + (size_t)1536 * DD, bo,
        (float*)d_out, nullptr, nullptr, nullptr, nullptr);
}

// Round 13
// 716.586 us; speedup vs baseline: 2.0424x; 1.0711x over previous
//
#include <hip/hip_runtime.h>
#include <hip/hip_bf16.h>
#include <math.h>

// Problem constants (fixed by the reference)
#define TT   799
#define BB   8
#define DD   512
#define HH   8
#define HDD  64
#define MMEM 6
#define RRCB 24
#define KLL  798
#define TQ   798            // query rows actually needed (row 798 unused)
#define NROWS (TQ * BB)     // 6384
#define NHEADS 64           // B*H
#define NEG_INF (-INFINITY)

#define TB   16             // t-rows per attention block
#define CH   64             // keys per MFMA chunk
#define NCH  13             // 13*64 = 832 >= 798
#define VTS  832            // v_t row stride in keys

static_assert(NROWS == 6384, "");

typedef __attribute__((ext_vector_type(8))) short short8;
typedef __attribute__((ext_vector_type(4))) float f32x4;

__device__ __forceinline__ unsigned short f2bf(float x) {
    union { float f; unsigned u; } c; c.f = x;
    unsigned r = c.u + 0x7FFFu + ((c.u >> 16) & 1u);   // RNE
    return (unsigned short)(r >> 16);
}
__device__ __forceinline__ float bf2f(unsigned short b) {
    union { unsigned u; float f; } c; c.u = ((unsigned)b) << 16; return c.f;
}

// mode 0 = int32 (0/1), mode 1 = float32 (0.0/1.0), mode 2 = uint8 bool.
__global__ void detect_mask_kernel(const unsigned int* __restrict__ a,
                                   int* __restrict__ mode)
{
    __shared__ int c0s, cHs;
    if (threadIdx.x == 0) { c0s = 0; cHs = 0; }
    __syncthreads();
    int c0 = 0, cH = 0;
    const int ND = 4096;
    for (int i = threadIdx.x; i < ND; i += blockDim.x) {
        unsigned int w = a[i];
        if (w & 0x000000FFu) c0++;
        if (w & 0xFFFFFF00u) cH++;
    }
    atomicAdd(&c0s, c0); atomicAdd(&cHs, cH);
    __syncthreads();
    if (threadIdx.x == 0)
        *mode = (cHs == 0) ? 0 : ((c0s == 0) ? 1 : 2);
}

// Fused prep: pack (mask,rpe)->rid bytes | rpe_k hi/lo split | x/mems/W hi/lo split.
#define PK_BLOCKS 625
#define RK_BLOCKS 36
__global__ __launch_bounds__(256)
void prep_kernel(const void* __restrict__ amask,
                 const int* __restrict__ rpe,
                 const int* __restrict__ mode_p,
                 unsigned int* __restrict__ pk,
                 const float* __restrict__ rpe_k,
                 unsigned short* __restrict__ rk_hi,
                 unsigned short* __restrict__ rk_lo,
                 const float* __restrict__ x,
                 const float* __restrict__ mems,
                 const float* __restrict__ wq,
                 const float* __restrict__ wkv,
                 const float* __restrict__ wo,
                 unsigned short* __restrict__ xs_hi, unsigned short* __restrict__ xs_lo,
                 unsigned short* __restrict__ ms_hi, unsigned short* __restrict__ ms_lo,
                 unsigned short* __restrict__ w_hi,  unsigned short* __restrict__ w_lo)
{
    const int bid = blockIdx.x;
    const int tid = threadIdx.x;
    if (bid < PK_BLOCKS) {
        const int mode = *mode_p;
        int i = bid * 256 + tid;
        if (i >= TT * 200) return;
        int t = i / 200;
        int kbase = (i - t * 200) * 4;
        unsigned out = 0;
        #pragma unroll
        for (int u = 0; u < 4; ++u) {
            int k = kbase + u;
            unsigned byte = 255u;
            if (k < KLL) {
                size_t idx = (size_t)t * KLL + k;
                bool masked;
                if (mode == 0)      masked = (((const int*)amask)[idx] != 0);
                else if (mode == 1) masked = (((const float*)amask)[idx] != 0.f);
                else                masked = (((const unsigned char*)amask)[idx] != 0);
                byte = masked ? 255u : (unsigned)rpe[idx];
            }
            out |= byte << (8 * u);
        }
        pk[i] = out;
    } else if (bid < PK_BLOCKS + RK_BLOCKS) {
        int i = (bid - PK_BLOCKS) * 256 + tid;
        if (i >= 144 * 64) return;
        int c = i >> 6;
        float v = (c < 129) ? rpe_k[i] : 0.f;
        unsigned short hi = f2bf(v);
        rk_hi[i] = hi;
        rk_lo[i] = f2bf(v - bf2f(hi));
    } else {
        const size_t NX = (size_t)NROWS * DD;
        const size_t NM = 48 * DD;
        const size_t NW = 2048 * DD;
        size_t i = (size_t)(bid - PK_BLOCKS - RK_BLOCKS) * 256 + tid;
        float v; unsigned short *dh, *dl; size_t o;
        if (i < NX) { o = i; v = x[o]; dh = xs_hi; dl = xs_lo; }
        else if (i < NX + NM) { o = i - NX; v = mems[o]; dh = ms_hi; dl = ms_lo; }
        else if (i < NX + NM + NW) {
            o = i - NX - NM;
            size_t r = o >> 9;
            if (r < 512) v = wq[o];
            else if (r < 1536) v = wkv[o - (size_t)512 * DD];
            else v = wo[o - (size_t)1536 * DD];
            dh = w_hi; dl = w_lo;
        } else return;
        unsigned short hi = f2bf(v);
        dh[o] = hi;
        dl[o] = f2bf(v - bf2f(hi));
    }
}

// v row-major bf16 hi/lo [head][key][hd] -> v_t [head][hd][VTS] (keys 798..831 zero)
__global__ __launch_bounds__(256)
void transpose_v_kernel(const unsigned short* __restrict__ vr_hi,
                        const unsigned short* __restrict__ vr_lo,
                        unsigned short* __restrict__ vt_hi,
                        unsigned short* __restrict__ vt_lo)
{
    const int head = blockIdx.y;
    const int kb = blockIdx.x * 64;
    __shared__ unsigned short th[64][66];
    __shared__ unsigned short tl[64][66];
    const int tid = threadIdx.x;
    for (int i = tid; i < 64 * 64; i += 256) {
        int ky = i >> 6, hd = i & 63;
        int key = kb + ky;
        unsigned short hv = 0, lv = 0;
        if (key < KLL) {
            size_t o = ((size_t)head * KLL + key) * HDD + hd;
            hv = vr_hi[o]; lv = vr_lo[o];
        }
        th[ky][hd] = hv; tl[ky][hd] = lv;
    }
    __syncthreads();
    for (int i = tid; i < 64 * 64; i += 256) {
        int hd = i >> 6, ky = i & 63;
        size_t o = ((size_t)head * HDD + hd) * VTS + kb + ky;
        vt_hi[o] = th[ky][hd];
        vt_lo[o] = tl[ky][hd];
    }
}

// MFMA GEMM: C[m][n] = A[m][:] . W[n][:] + bias, bf16 hi/lo split (3 cross terms).
// MODE 0: A = xs, out q hi/lo (scaled 0.125). MODE 1: A = mem_rc (ms|xs),
// out k hi/lo (n<512) or vr hi/lo. MODE 2: A = ao, out f32 (+tanh tail rows).
template<int MODE>
__global__ __launch_bounds__(256)
void mfma_proj(const unsigned short* __restrict__ a_hi,
               const unsigned short* __restrict__ a_lo,
               const unsigned short* __restrict__ ms_hi,
               const unsigned short* __restrict__ ms_lo,
               const unsigned short* __restrict__ w_hi,
               const unsigned short* __restrict__ w_lo,
               const float* __restrict__ bias,
               float* __restrict__ out_f,
               unsigned short* __restrict__ oa_hi, unsigned short* __restrict__ oa_lo,
               unsigned short* __restrict__ ob_hi, unsigned short* __restrict__ ob_lo)
{
    const int tid = threadIdx.x;
    const int wv = tid >> 6;
    const int quad = (tid >> 4) & 3;
    const int colk = tid & 15;
    const int m0 = blockIdx.x * 64;
    const int n0 = blockIdx.y * 64;

    const int am = min(m0 + wv * 16 + colk, NROWS - 1);
    const unsigned short *arh, *arl;
    if (MODE == 1) {
        if (am < 48) { arh = ms_hi + (size_t)am * DD; arl = ms_lo + (size_t)am * DD; }
        else         { arh = a_hi + (size_t)(am - 48) * DD; arl = a_lo + (size_t)(am - 48) * DD; }
    } else {
        arh = a_hi + (size_t)am * DD; arl = a_lo + (size_t)am * DD;
    }

    f32x4 acc[4] = {{0,0,0,0},{0,0,0,0},{0,0,0,0},{0,0,0,0}};

    #pragma unroll 2
    for (int k0 = 0; k0 < DD; k0 += 32) {
        short8 ah = *(const short8*)(arh + k0 + quad * 8);
        short8 al = *(const short8*)(arl + k0 + quad * 8);
        #pragma unroll
        for (int nt = 0; nt < 4; ++nt) {
            const size_t wb = (size_t)(n0 + nt * 16 + colk) * DD + k0 + quad * 8;
            short8 bh = *(const short8*)(w_hi + wb);
            short8 bl = *(const short8*)(w_lo + wb);
            acc[nt] = __builtin_amdgcn_mfma_f32_16x16x32_bf16(ah, bh, acc[nt], 0, 0, 0);
            acc[nt] = __builtin_amdgcn_mfma_f32_16x16x32_bf16(ah, bl, acc[nt], 0, 0, 0);
            acc[nt] = __builtin_amdgcn_mfma_f32_16x16x32_bf16(al, bh, acc[nt], 0, 0, 0);
        }
    }

    #pragma unroll
    for (int nt = 0; nt < 4; ++nt) {
        const int nn = n0 + nt * 16 + colk;
        const float bv = bias[nn];
        #pragma unroll
        for (int reg = 0; reg < 4; ++reg) {
            const int m = m0 + wv * 16 + quad * 4 + reg;
            if (m >= NROWS) continue;
            float v = acc[nt][reg] + bv;
            if (MODE == 0) {
                v *= 0.125f;
                int row = m >> 3, bb = m & 7, hh = nn >> 6, hd = nn & 63;
                size_t o = ((size_t)(bb * HH + hh) * TQ + row) * HDD + hd;
                unsigned short hi = f2bf(v);
                oa_hi[o] = hi; oa_lo[o] = f2bf(v - bf2f(hi));
            } else if (MODE == 1) {
                int row = m >> 3, bb = m & 7;
                if (nn < DD) {
                    int hh = nn >> 6, hd = nn & 63;
                    size_t o = ((size_t)(bb * HH + hh) * KLL + row) * HDD + hd;
                    unsigned short hi = f2bf(v);
                    oa_hi[o] = hi; oa_lo[o] = f2bf(v - bf2f(hi));
                } else {
                    int n2 = nn - DD;
                    int hh = n2 >> 6, hd = n2 & 63;
                    size_t o = ((size_t)(bb * HH + hh) * KLL + row) * HDD + hd;
                    unsigned short hi = f2bf(v);
                    ob_hi[o] = hi; ob_lo[o] = f2bf(v - bf2f(hi));
                }
            } else {
                int row = m >> 3;
                if (row >= TQ - MMEM) v = tanhf(v);
                out_f[(size_t)m * DD + nn] = v;
            }
        }
    }
}

// Attention v9: all-MFMA, XCD-swizzled grid, no register spill:
// __launch_bounds__(256,3) raises the VGPR cap so s_reg stays in registers
// (R12's 124 MB scratch-spill traffic was the binder); pk stays in LDS
// through pass B (rid_pack registers dropped).
__global__ __launch_bounds__(256, 3)
void attn_kernel(const unsigned short* __restrict__ qh_g,
                 const unsigned short* __restrict__ ql_g,
                 const unsigned short* __restrict__ kh_g,
                 const unsigned short* __restrict__ kl_g,
                 const unsigned short* __restrict__ vt_hi,
                 const unsigned short* __restrict__ vt_lo,
                 const int* __restrict__ lengths,
                 const unsigned char* __restrict__ pk,
                 const unsigned short* __restrict__ rk_hi,
                 const unsigned short* __restrict__ rk_lo,
                 const float* __restrict__ rpe_v,
                 unsigned short* __restrict__ ao_hi,
                 unsigned short* __restrict__ ao_lo)
{
    // XCD-aware decode: xcd = id&7 fixed per head; t-chunks consecutive.
    const int id = blockIdx.x;
    const int xcd = id & 7;
    const int grp = id >> 3;             // 0..399
    const int t_chunk = grp % 50;
    const int n = (grp / 50) * 8 + xcd;  // head index 0..63
    const int t0 = t_chunk * TB;
    const int rows = min(TB, TQ - t0);
    const int b = n >> 3;
    const int h = n & 7;
    const int tid = threadIdx.x;
    const int wv = tid >> 6;
    const int quad = (tid >> 4) & 3;
    const int colk = tid & 15;
    const int myk = wv * 16 + colk;

    __shared__ float qrk_l[TB][132];                 // qrk, then pr buckets (8448 B)
    __shared__ unsigned char pk_l[TB][800];          // 12800 B, live all kernel
    __shared__ unsigned short p_hi[2][TB][72];       // 4608 B
    __shared__ unsigned short p_lo[2][TB][72];       // 4608 B
    __shared__ float4 stats_l[4][TB];                // 1024 B

    const int klen = lengths[b] + MMEM + RRCB;

    // phase 0: pk tile -> LDS
    for (int i = tid; i < TB * 200; i += 256) {
        int rr = i / 200, dw = i - rr * 200;
        unsigned w = 0xFFFFFFFFu;
        if (rr < rows) w = ((const unsigned*)pk)[(t0 + rr) * 200 + dw];
        ((unsigned*)&pk_l[rr][0])[dw] = w;
    }

    // A fragments (Q), direct global, held all kernel. A row = query row colk.
    const int qrow = t0 + min(colk, rows - 1);
    const size_t qo = ((size_t)n * TQ + qrow) * HDD;
    short8 ah0 = *(const short8*)(qh_g + qo + quad * 8);
    short8 ah1 = *(const short8*)(qh_g + qo + 32 + quad * 8);
    short8 al0 = *(const short8*)(ql_g + qo + quad * 8);
    short8 al1 = *(const short8*)(ql_g + qo + 32 + quad * 8);

    // qrk via MFMA: wave wv does rpe_k row-tiles wv, wv+4, wv+8
    for (int t = wv; t < 9; t += 4) {
        const size_t rb = (size_t)(t * 16 + colk) * 64;
        short8 bh0 = *(const short8*)(rk_hi + rb + quad * 8);
        short8 bh1 = *(const short8*)(rk_hi + rb + 32 + quad * 8);
        short8 bl0 = *(const short8*)(rk_lo + rb + quad * 8);
        short8 bl1 = *(const short8*)(rk_lo + rb + 32 + quad * 8);
        f32x4 c4 = {0.f, 0.f, 0.f, 0.f};
        c4 = __builtin_amdgcn_mfma_f32_16x16x32_bf16(ah0, bh0, c4, 0, 0, 0);
        c4 = __builtin_amdgcn_mfma_f32_16x16x32_bf16(ah1, bh1, c4, 0, 0, 0);
        c4 = __builtin_amdgcn_mfma_f32_16x16x32_bf16(ah0, bl0, c4, 0, 0, 0);
        c4 = __builtin_amdgcn_mfma_f32_16x16x32_bf16(ah1, bl1, c4, 0, 0, 0);
        c4 = __builtin_amdgcn_mfma_f32_16x16x32_bf16(al0, bh0, c4, 0, 0, 0);
        c4 = __builtin_amdgcn_mfma_f32_16x16x32_bf16(al1, bh1, c4, 0, 0, 0);
        int c = t * 16 + colk;
        if (c <= 128) {
            #pragma unroll
            for (int reg = 0; reg < 4; ++reg) qrk_l[quad * 4 + reg][c] = c4[reg];
        }
    }
    __syncthreads();

    // ---- pass A: QK^T MFMA, record scores + max ----
    float s_reg[NCH][4];
    float mx[4] = {-1e30f, -1e30f, -1e30f, -1e30f};

    #pragma unroll
    for (int cc = 0; cc < NCH; ++cc) {
        const int key = cc * CH + myk;
        const int krow = min(key, KLL - 1);
        const size_t ko = ((size_t)n * KLL + krow) * HDD;
        short8 bh0 = *(const short8*)(kh_g + ko + quad * 8);
        short8 bh1 = *(const short8*)(kh_g + ko + 32 + quad * 8);
        short8 bl0 = *(const short8*)(kl_g + ko + quad * 8);
        short8 bl1 = *(const short8*)(kl_g + ko + 32 + quad * 8);
        f32x4 c4 = {0.f, 0.f, 0.f, 0.f};
        c4 = __builtin_amdgcn_mfma_f32_16x16x32_bf16(ah0, bh0, c4, 0, 0, 0);
        c4 = __builtin_amdgcn_mfma_f32_16x16x32_bf16(ah1, bh1, c4, 0, 0, 0);
        c4 = __builtin_amdgcn_mfma_f32_16x16x32_bf16(ah0, bl0, c4, 0, 0, 0);
        c4 = __builtin_amdgcn_mfma_f32_16x16x32_bf16(ah1, bl1, c4, 0, 0, 0);
        c4 = __builtin_amdgcn_mfma_f32_16x16x32_bf16(al0, bh0, c4, 0, 0, 0);
        c4 = __builtin_amdgcn_mfma_f32_16x16x32_bf16(al1, bh1, c4, 0, 0, 0);

        const bool vkey = (key < klen);
        #pragma unroll
        for (int reg = 0; reg < 4; ++reg) {
            const int row = quad * 4 + reg;
            float s = -1e30f;
            if (vkey && row < rows) {
                unsigned rid = pk_l[row][key];
                if (rid != 255u) s = c4[reg] + qrk_l[row][rid];
            }
            mx[reg] = fmaxf(mx[reg], s);
            s_reg[cc][reg] = s;
        }
    }

    // max merge: shfl16 then cross-wave
    #pragma unroll
    for (int reg = 0; reg < 4; ++reg)
        #pragma unroll
        for (int d = 1; d < 16; d <<= 1) mx[reg] = fmaxf(mx[reg], __shfl_xor(mx[reg], d, 16));
    if (colk == 0) {
        #pragma unroll
        for (int reg = 0; reg < 4; ++reg)
            stats_l[wv][quad * 4 + reg] = make_float4(mx[reg], 0.f, 0.f, 0.f);
    }
    __syncthreads();
    if (tid < TB) {
        float M = fmaxf(fmaxf(stats_l[0][tid].x, stats_l[1][tid].x),
                        fmaxf(stats_l[2][tid].x, stats_l[3][tid].x));
        stats_l[0][tid].x = M;
    }
    __syncthreads();

    // e-sweep: e = exp(s - M), overwrite s_reg; accumulate l, l2, count
    float Mr[4], l[4] = {0,0,0,0}, l2[4] = {0,0,0,0}, cn[4] = {0,0,0,0};
    #pragma unroll
    for (int reg = 0; reg < 4; ++reg) Mr[reg] = stats_l[0][quad * 4 + reg].x;
    #pragma unroll
    for (int cc = 0; cc < NCH; ++cc) {
        #pragma unroll
        for (int reg = 0; reg < 4; ++reg) {
            float s = s_reg[cc][reg];
            float e = 0.f;
            if (s > -1e29f) { e = expf(s - Mr[reg]); cn[reg] += 1.f; }
            l[reg] += e;
            l2[reg] = fmaf(e, e, l2[reg]);
            s_reg[cc][reg] = e;
        }
    }
    #pragma unroll
    for (int reg = 0; reg < 4; ++reg)
        #pragma unroll
        for (int d = 1; d < 16; d <<= 1) {
            l[reg]  += __shfl_xor(l[reg], d, 16);
            l2[reg] += __shfl_xor(l2[reg], d, 16);
            cn[reg] += __shfl_xor(cn[reg], d, 16);
        }
    if (colk == 0) {
        #pragma unroll
        for (int reg = 0; reg < 4; ++reg)
            stats_l[wv][quad * 4 + reg] = make_float4(Mr[reg], l[reg], l2[reg], cn[reg]);
    }
    __syncthreads();
    if (tid < TB) {
        float L = 0.f, L2 = 0.f, C = 0.f;
        #pragma unroll
        for (int w = 0; w < 4; ++w) {
            float4 s4 = stats_l[w][tid];
            L += s4.y; L2 += s4.z; C += s4.w;
        }
        float inv = (L > 0.f) ? 1.f / L : 0.f;
        float mean = 1.f / (C + 1e-8f);
        float sump2 = L2 * inv * inv;
        float var = (sump2 - 2.f * mean + C * mean * mean) / (C - 1.f + 1e-8f);
        var = fmaxf(var, 0.f);
        float thr = mean - 0.5f * sqrtf(var);
        stats_l[0][tid] = make_float4(stats_l[0][tid].x, inv, thr, 0.f);
    }
    // zero pr (qrk_l reuse)
    for (int i = tid; i < TB * 132; i += 256) ((float*)qrk_l)[i] = 0.f;
    __syncthreads();

    // ---- pass B: p = e*inv, threshold, buckets, PV via MFMA ----
    float inv_r[4], thr_r[4];
    #pragma unroll
    for (int reg = 0; reg < 4; ++reg) {
        float4 s4 = stats_l[0][quad * 4 + reg];
        inv_r[reg] = s4.y; thr_r[reg] = s4.z;
    }
    float sig[4] = {0.f, 0.f, 0.f, 0.f};
    f32x4 oacc = {0.f, 0.f, 0.f, 0.f};

    auto computeP = [&](int cc, int buf) {
        const int key = cc * CH + myk;
        #pragma unroll
        for (int reg = 0; reg < 4; ++reg) {
            const int row = quad * 4 + reg;
            float p = s_reg[cc][reg] * inv_r[reg];
            if (p < thr_r[reg]) p = 0.f;
            if (p > 0.f) {
                sig[reg] += p;
                atomicAdd(&qrk_l[row][pk_l[row][key]], p);
            }
            unsigned short ph = f2bf(p);
            p_hi[buf][row][myk] = ph;
            p_lo[buf][row][myk] = f2bf(p - bf2f(ph));
        }
    };

    computeP(0, 0);
    __syncthreads();
    for (int cc = 0; cc < NCH; ++cc) {
        const int buf = cc & 1;
        const size_t vbase = ((size_t)n * HDD + wv * 16 + colk) * VTS + cc * CH;
        short8 vh0 = *(const short8*)(vt_hi + vbase + quad * 8);
        short8 vh1 = *(const short8*)(vt_hi + vbase + 32 + quad * 8);
        short8 vl0 = *(const short8*)(vt_lo + vbase + quad * 8);
        short8 vl1 = *(const short8*)(vt_lo + vbase + 32 + quad * 8);
        short8 ph0 = *(const short8*)&p_hi[buf][colk][quad * 8];
        short8 ph1 = *(const short8*)&p_hi[buf][colk][32 + quad * 8];
        short8 pl0 = *(const short8*)&p_lo[buf][colk][quad * 8];
        short8 pl1 = *(const short8*)&p_lo[buf][colk][32 + quad * 8];
        oacc = __builtin_amdgcn_mfma_f32_16x16x32_bf16(vh0, ph0, oacc, 0, 0, 0);
        oacc = __builtin_amdgcn_mfma_f32_16x16x32_bf16(vh1, ph1, oacc, 0, 0, 0);
        oacc = __builtin_amdgcn_mfma_f32_16x16x32_bf16(vh0, pl0, oacc, 0, 0, 0);
        oacc = __builtin_amdgcn_mfma_f32_16x16x32_bf16(vh1, pl1, oacc, 0, 0, 0);
        oacc = __builtin_amdgcn_mfma_f32_16x16x32_bf16(vl0, ph0, oacc, 0, 0, 0);
        oacc = __builtin_amdgcn_mfma_f32_16x16x32_bf16(vl1, ph1, oacc, 0, 0, 0);
        if (cc + 1 < NCH) computeP(cc + 1, (cc + 1) & 1);
        __syncthreads();
    }

    // survivor-sum merge
    #pragma unroll
    for (int reg = 0; reg < 4; ++reg)
        #pragma unroll
        for (int d = 1; d < 16; d <<= 1) sig[reg] += __shfl_xor(sig[reg], d, 16);
    if (colk == 0) {
        #pragma unroll
        for (int reg = 0; reg < 4; ++reg)
            stats_l[wv][quad * 4 + reg].w = sig[reg];
    }
    __syncthreads();
    if (tid < TB) {
        float S = stats_l[0][tid].w + stats_l[1][tid].w + stats_l[2][tid].w + stats_l[3][tid].w;
        stats_l[0][tid].w = (S > 0.f) ? 1.f / S : 0.f;
    }
    __syncthreads();

    // output: lane owns O[row=colk][hd = wv*16 + quad*4 .. +3], bf16 hi/lo
    if (colk < rows) {
        float4 ar = {0.f, 0.f, 0.f, 0.f};
        const int hdb = wv * 16 + quad * 4;
        for (int c = 0; c < 129; ++c) {
            float p = qrk_l[colk][c];
            if (p != 0.f) {
                float4 v4 = *(const float4*)(rpe_v + (size_t)c * HDD + hdb);
                ar.x = fmaf(p, v4.x, ar.x);
                ar.y = fmaf(p, v4.y, ar.y);
                ar.z = fmaf(p, v4.z, ar.z);
                ar.w = fmaf(p, v4.w, ar.w);
            }
        }
        const float invS = stats_l[0][colk].w;
        float o0 = (2.f * oacc[0] + ar.x) * invS;
        float o1 = (2.f * oacc[1] + ar.y) * invS;
        float o2 = (2.f * oacc[2] + ar.z) * invS;
        float o3 = (2.f * oacc[3] + ar.w) * invS;
        size_t oo = ((size_t)(t0 + colk) * BB + b) * DD + h * HDD + hdb;
        ushort4 oh, ol;
        oh.x = f2bf(o0); ol.x = f2bf(o0 - bf2f(oh.x));
        oh.y = f2bf(o1); ol.y = f2bf(o1 - bf2f(oh.y));
        oh.z = f2bf(o2); ol.z = f2bf(o2 - bf2f(oh.z));
        oh.w = f2bf(o3); ol.w = f2bf(o3 - bf2f(oh.w));
        *(ushort4*)(ao_hi + oo) = oh;
        *(ushort4*)(ao_lo + oo) = ol;
    }
}

extern "C" void kernel_launch(void* const* d_in, const int* in_sizes, int n_in,
                              void* d_out, int out_size, void* d_ws, size_t ws_size,
                              hipStream_t stream) {
    const float*          x      = (const float*)d_in[0];
    const int*            lengths= (const int*)d_in[1];
    const float*          mems   = (const float*)d_in[2];
    const void*           amask  = (const void*)d_in[3];
    const int*            rpe    = (const int*)d_in[4];
    const float*          wq     = (const float*)d_in[6];
    const float*          bq     = (const float*)d_in[7];
    const float*          wkv    = (const float*)d_in[8];
    const float*          bkv    = (const float*)d_in[9];
    const float*          wo     = (const float*)d_in[10];
    const float*          bo     = (const float*)d_in[11];
    const float*          rpe_k  = (const float*)d_in[12];
    const float*          rpe_v  = (const float*)d_in[13];

    const size_t NE = (size_t)NROWS * DD;           // 3,268,608
    const size_t VTN = (size_t)NHEADS * HDD * VTS;  // 3,407,872

    char* p = (char*)d_ws;
    unsigned short* q_hi = (unsigned short*)p;  p += NE * 2;
    unsigned short* q_lo = (unsigned short*)p;  p += NE * 2;
    // union region: xs/ms (proj inputs, dead after proj1) | vt (written after)
    char* uni = p;                              p += VTN * 4;   // vt is the larger
    unsigned short* xs_hi = (unsigned short*)uni;
    unsigned short* xs_lo = xs_hi + NE;
    unsigned short* ms_hi = xs_lo + NE;
    unsigned short* ms_lo = ms_hi + 48 * DD;
    unsigned short* vt_hi = (unsigned short*)uni;
    unsigned short* vt_lo = vt_hi + VTN;
    unsigned short* w_hi = (unsigned short*)p;  p += (size_t)2048 * DD * 2;
    unsigned short* w_lo = (unsigned short*)p;  p += (size_t)2048 * DD * 2;
    unsigned short* k_hi = (unsigned short*)p;  p += NE * 2;
    unsigned short* k_lo = (unsigned short*)p;  p += NE * 2;
    unsigned short* vr_hi = (unsigned short*)p; p += NE * 2;   // aliased by ao after transpose
    unsigned short* vr_lo = (unsigned short*)p; p += NE * 2;
    unsigned short* ao_hi = vr_hi;
    unsigned short* ao_lo = vr_lo;
    unsigned short* rk_hi = (unsigned short*)p; p += 144 * 64 * 2;
    unsigned short* rk_lo = (unsigned short*)p; p += 144 * 64 * 2;
    unsigned char*  pk    = (unsigned char*)p;  p += (size_t)TT * 800;
    int* mmode = (int*)p;

    detect_mask_kernel<<<1, 1024, 0, stream>>>((const unsigned int*)amask, mmode);
    {
        const size_t sp_total = NE + (size_t)48 * DD + (size_t)2048 * DD;  // 4,341,760
        const int sp_blocks = (int)((sp_total + 255) / 256);               // 16,960
        prep_kernel<<<PK_BLOCKS + RK_BLOCKS + sp_blocks, 256, 0, stream>>>(
            amask, rpe, mmode, (unsigned int*)pk,
            rpe_k, rk_hi, rk_lo,
            x, mems, wq, wkv, wo,
            xs_hi, xs_lo, ms_hi, ms_lo, w_hi, w_lo);
    }
    mfma_proj<0><<<dim3(100, 8), 256, 0, stream>>>(
        xs_hi, xs_lo, nullptr, nullptr, w_hi, w_lo, bq,
        nullptr, q_hi, q_lo, nullptr, nullptr);
    mfma_proj<1><<<dim3(100, 16), 256, 0, stream>>>(
        xs_hi, xs_lo, ms_hi, ms_lo, w_hi + (size_t)512 * DD, w_lo + (size_t)512 * DD, bkv,
        nullptr, k_hi, k_lo, vr_hi, vr_lo);
    transpose_v_kernel<<<dim3(13, NHEADS), 256, 0, stream>>>(vr_hi, vr_lo, vt_hi, vt_lo);
    attn_kernel<<<3200, 256, 0, stream>>>(
        q_hi, q_lo, k_hi, k_lo, vt_hi, vt_lo, lengths, pk, rk_hi, rk_lo, rpe_v, ao_hi, ao_lo);
    mfma_proj<2><<<dim3(100, 8), 256, 0, stream>>>(
        ao_hi, ao_lo, nullptr, nullptr, w_hi + (size_t)1536 * DD, w_lo + (size_t)1536 * DD, bo,
        (float*)d_out, nullptr, nullptr, nullptr, nullptr);
}